// Round 16
// baseline (931.964 us; speedup 1.0000x reference)
//
#include <hip/hip_runtime.h>
#include <cstdint>

#define DEV static __device__ __forceinline__

typedef unsigned short u16;
typedef __attribute__((ext_vector_type(8))) short short8;
typedef __attribute__((ext_vector_type(4))) float f32x4;

namespace cfg {
constexpr int V = 32000, D = 1024, H = 16, F = 4096, L = 3, T = 1024, B = 2;
constexpr int N = B * T;     // 2048 token rows
constexpr int HD = D / H;    // 64
}

DEV float bf2f(u16 b) { union { unsigned u; float f; } x; x.u = (unsigned)b << 16; return x.f; }
DEV u16 f2bf(float f) {
  union { float f; unsigned u; } x; x.f = f;
  unsigned u = x.u;
  return (u16)((u + 0x7fffu + ((u >> 16) & 1u)) >> 16);
}

DEV void gload16(void* lds, const void* g) {
  __builtin_amdgcn_global_load_lds((__attribute__((address_space(1))) void*)g,
                                   (__attribute__((address_space(3))) void*)lds, 16, 0, 0);
}

template <int NW>
DEV void waitVm() {
  if constexpr (NW == 0) asm volatile("s_waitcnt vmcnt(0)" ::: "memory");
  else if constexpr (NW == 3) asm volatile("s_waitcnt vmcnt(3)" ::: "memory");
  else if constexpr (NW == 4) asm volatile("s_waitcnt vmcnt(4)" ::: "memory");
  else if constexpr (NW == 6) asm volatile("s_waitcnt vmcnt(6)" ::: "memory");
  else if constexpr (NW == 8) asm volatile("s_waitcnt vmcnt(8)" ::: "memory");
  __builtin_amdgcn_sched_barrier(0);
}
DEV void barrierRaw() {
  __builtin_amdgcn_sched_barrier(0);
  __builtin_amdgcn_s_barrier();
  __builtin_amdgcn_sched_barrier(0);
}
DEV void waitLgkm0() {
  asm volatile("s_waitcnt lgkmcnt(0)" ::: "memory");
  __builtin_amdgcn_sched_barrier(0);
}

DEV float waveSum(float v) {
#pragma unroll
  for (int o = 32; o; o >>= 1) v += __shfl_xor(v, o);
  return v;
}

// ---------------- weight fp32 -> bf16 cast (batched jobs) ----------------
struct CastJob { const float* src; u16* dst; int nBlk; };
struct CastArgs { CastJob j[24]; int n; };

__global__ void cast_kernel(CastArgs a) {
  int blk = blockIdx.x;
  int i = 0;
  while (i + 1 < a.n && blk >= a.j[i].nBlk) { blk -= a.j[i].nBlk; ++i; }
  const size_t base = (size_t)blk * 2048 + threadIdx.x * 8;
  const float4* s4 = (const float4*)(a.j[i].src + base);
  const float4 v0 = s4[0], v1 = s4[1];
  short8 o;
  o[0] = (short)f2bf(v0.x); o[1] = (short)f2bf(v0.y);
  o[2] = (short)f2bf(v0.z); o[3] = (short)f2bf(v0.w);
  o[4] = (short)f2bf(v1.x); o[5] = (short)f2bf(v1.y);
  o[6] = (short)f2bf(v1.z); o[7] = (short)f2bf(v1.w);
  *(short8*)(a.j[i].dst + base) = o;
}

// ---------------- small fp32 copy (bias concat) ----------------
struct CopyJob { const float* src; float* dst; };
struct CopyArgs { CopyJob j[16]; int n; };
__global__ void bconcat_kernel(CopyArgs a) {
  const CopyJob jb = a.j[blockIdx.x];
  ((float4*)jb.dst)[threadIdx.x] = ((const float4*)jb.src)[threadIdx.x];
}

// ---------------- embedding: h = tok_W[x] + pos ----------------
__global__ void embed_kernel(const int* __restrict__ x, const float* __restrict__ tokW,
                             const float* __restrict__ pos, float* __restrict__ hF,
                             u16* __restrict__ hB) {
  const int bt = blockIdx.x;
  const int t = bt & (cfg::T - 1);
  const int tid = threadIdx.x;
  const int idx = x[bt];
  float4 v = ((const float4*)(tokW + (size_t)idx * cfg::D))[tid];
  const float4 p = ((const float4*)(pos + (size_t)t * cfg::D))[tid];
  v.x += p.x; v.y += p.y; v.z += p.z; v.w += p.w;
  ((float4*)(hF + (size_t)bt * cfg::D))[tid] = v;
  union { u16 u[4]; uint2 q; } pk;
  pk.u[0] = f2bf(v.x); pk.u[1] = f2bf(v.y); pk.u[2] = f2bf(v.z); pk.u[3] = f2bf(v.w);
  *(uint2*)(hB + (size_t)bt * cfg::D + tid * 4) = pk.q;
}

// ---------------- residual + (sum of NADD split-K partials) + bias + LayerNorm ----------------
template <int NADD>
__global__ void ln_kernel(const float* __restrict__ base,
                          const float* __restrict__ a0, const float* __restrict__ a1,
                          const float* __restrict__ a2, const float* __restrict__ a3,
                          const float* __restrict__ biasv,
                          const float* __restrict__ g, const float* __restrict__ bt,
                          float* __restrict__ outF, u16* __restrict__ outB) {
  const int row = blockIdx.x, tid = threadIdx.x;
  const int lane = tid & 63, wid = tid >> 6;
  const size_t roff = (size_t)row * cfg::D;
  float4 x = ((const float4*)(base + roff))[tid];
  if (NADD >= 1) {
    const float4 a = ((const float4*)(a0 + roff))[tid];
    x.x += a.x; x.y += a.y; x.z += a.z; x.w += a.w;
  }
  if (NADD >= 2) {
    const float4 a = ((const float4*)(a1 + roff))[tid];
    x.x += a.x; x.y += a.y; x.z += a.z; x.w += a.w;
  }
  if (NADD >= 3) {
    const float4 a = ((const float4*)(a2 + roff))[tid];
    x.x += a.x; x.y += a.y; x.z += a.z; x.w += a.w;
  }
  if (NADD >= 4) {
    const float4 a = ((const float4*)(a3 + roff))[tid];
    x.x += a.x; x.y += a.y; x.z += a.z; x.w += a.w;
  }
  if (biasv) {
    const float4 a = ((const float4*)biasv)[tid];
    x.x += a.x; x.y += a.y; x.z += a.z; x.w += a.w;
  }
  float s = x.x + x.y + x.z + x.w;
  float s2 = x.x * x.x + x.y * x.y + x.z * x.z + x.w * x.w;
  __shared__ float sb[8];
  s = waveSum(s); s2 = waveSum(s2);
  if (lane == 0) { sb[wid] = s; sb[4 + wid] = s2; }
  __syncthreads();
  s = sb[0] + sb[1] + sb[2] + sb[3];
  s2 = sb[4] + sb[5] + sb[6] + sb[7];
  const float mean = s * (1.f / cfg::D);
  const float rs = rsqrtf(s2 * (1.f / cfg::D) - mean * mean + 1e-5f);
  const float4 gv = ((const float4*)g)[tid];
  const float4 bv = ((const float4*)bt)[tid];
  float4 y;
  y.x = (x.x - mean) * rs * gv.x + bv.x;
  y.y = (x.y - mean) * rs * gv.y + bv.y;
  y.z = (x.z - mean) * rs * gv.z + bv.z;
  y.w = (x.w - mean) * rs * gv.w + bv.w;
  ((float4*)(outF + roff))[tid] = y;
  union { u16 u[4]; uint2 q; } pk;
  pk.u[0] = f2bf(y.x); pk.u[1] = f2bf(y.y); pk.u[2] = f2bf(y.z); pk.u[3] = f2bf(y.w);
  *(uint2*)(outB + roff + tid * 4) = pk.q;
}

// ---------------- V transpose: picks v-slice, [B,T,D3]->[B*H, HD, T] ----------------
__global__ void vtrans_kernel(const u16* __restrict__ v, u16* __restrict__ vtO, int vstride) {
  __shared__ u16 s[64][68];
  const int bh = blockIdx.y, b = bh >> 4, h = bh & 15;
  const int t0 = blockIdx.x * 64;
  const int tid = threadIdx.x;
  const int r2 = tid >> 3, cg = tid & 7;
#pragma unroll
  for (int p = 0; p < 2; ++p) {
    const int r = p * 32 + r2;
    const short8 val = *(const short8*)(v + (size_t)(b * cfg::T + t0 + r) * vstride + h * 64 + cg * 8);
#pragma unroll
    for (int j = 0; j < 8; ++j) s[r][cg * 8 + j] = (u16)val[j];
  }
  __syncthreads();
#pragma unroll
  for (int p = 0; p < 2; ++p) {
    const int d = p * 32 + r2;
    short8 o;
#pragma unroll
    for (int j = 0; j < 8; ++j) o[j] = (short)s[cg * 8 + j][d];
    *(short8*)(vtO + ((size_t)bh * 64 + d) * (size_t)cfg::T + t0 + cg * 8) = o;
  }
}

// ---------------- swizzled LDS staging, 128B rows ----------------
template <int NCH>
DEV void stageTile(u16* lds, const u16* src, int strideElems, int tid) {
#pragma unroll
  for (int c = 0; c < NCH / 256; ++c) {
    const int ci = c * 256 + tid;
    const int r = ci >> 3;
    const int c8 = ci & 7;
    const int sc8 = c8 ^ (r & 7);
    gload16(lds + (size_t)ci * 8, src + (size_t)r * strideElems + sc8 * 8);
  }
}
DEV short8 ldsFrag(const u16* tile, int row, int kElem) {
  const int byteoff = row * 128 + ((kElem * 2) ^ ((row & 7) << 4));
  return *(const short8*)((const char*)tile + byteoff);
}
// 64B rows (BK=32): residual 2-way bank aliasing only (free).
DEV short8 ldsFrag32(const u16* tile, int row, int kElem) {
  const int byteoff = row * 64 + ((kElem * 2) ^ (((row >> 1) & 3) << 4));
  return *(const short8*)((const char*)tile + byteoff);
}

// ---------------- flash attention: QBLK=64, grid (T/64, B*H), 256 thr ----------------
__launch_bounds__(256, 3)
__global__ void fattn_kernel(const u16* __restrict__ qkv, const u16* __restrict__ vt,
                             u16* __restrict__ o) {
  constexpr int D3 = 3 * cfg::D;
  __shared__ u16 Qs[64 * 64];
  __shared__ u16 Ks[64 * 64];
  __shared__ u16 Vs[64 * 64];
  __shared__ u16 Ps[64][72];
  const int tid = threadIdx.x, lane = tid & 63, w = tid >> 6;
  const int qt = gridDim.x - 1 - blockIdx.x;   // longest-first scheduling
  const int bh = blockIdx.y;
  const int b = bh >> 4, h = bh & 15;
  const int q0 = qt * 64;
  const int l15 = lane & 15, lq = lane >> 4;

  stageTile<512>(Qs, qkv + (size_t)(b * cfg::T + q0) * D3 + h * 64, D3, tid);
  __syncthreads();
  short8 qf[2];
#pragma unroll
  for (int kk = 0; kk < 2; ++kk)
    qf[kk] = ldsFrag(Qs, w * 16 + l15, kk * 32 + lq * 8);

  f32x4 oa[4];
  float m[4], l[4];
#pragma unroll
  for (int r = 0; r < 4; ++r) { m[r] = -1e30f; l[r] = 0.f; }
#pragma unroll
  for (int nt = 0; nt < 4; ++nt) { oa[nt][0] = 0; oa[nt][1] = 0; oa[nt][2] = 0; oa[nt][3] = 0; }

  const int nkt = qt + 1;
  const u16* kbase = qkv + (size_t)(b * cfg::T) * D3 + cfg::D + h * 64;
  const u16* vbase = vt + (size_t)bh * 64 * cfg::T;

  for (int kt = 0; kt < nkt; ++kt) {
    const int k0 = kt * 64;
    __syncthreads();
    stageTile<512>(Ks, kbase + (size_t)k0 * D3, D3, tid);
    stageTile<512>(Vs, vbase + k0, cfg::T, tid);
    __syncthreads();

    f32x4 sa[4];
#pragma unroll
    for (int nt = 0; nt < 4; ++nt) { sa[nt][0] = 0; sa[nt][1] = 0; sa[nt][2] = 0; sa[nt][3] = 0; }
#pragma unroll
    for (int kk = 0; kk < 2; ++kk) {
      short8 kf[4];
#pragma unroll
      for (int nt = 0; nt < 4; ++nt) kf[nt] = ldsFrag(Ks, nt * 16 + l15, kk * 32 + lq * 8);
#pragma unroll
      for (int nt = 0; nt < 4; ++nt)
        sa[nt] = __builtin_amdgcn_mfma_f32_16x16x32_bf16(qf[kk], kf[nt], sa[nt], 0, 0, 0);
    }

    const bool needMask = (kt >= qt);
#pragma unroll
    for (int r = 0; r < 4; ++r) {
      const int qrow = q0 + w * 16 + lq * 4 + r;
      float s[4];
#pragma unroll
      for (int nt = 0; nt < 4; ++nt) {
        s[nt] = sa[nt][r] * 0.125f;
        if (needMask && (k0 + nt * 16 + l15 > qrow)) s[nt] = -3e38f;
      }
      float rm = fmaxf(fmaxf(s[0], s[1]), fmaxf(s[2], s[3]));
#pragma unroll
      for (int off = 1; off < 16; off <<= 1) rm = fmaxf(rm, __shfl_xor(rm, off));
      const float mn = fmaxf(m[r], rm);
      const float sc = __expf(m[r] - mn);
      m[r] = mn;
      float ps = 0.f;
#pragma unroll
      for (int nt = 0; nt < 4; ++nt) {
        const float p = __expf(s[nt] - mn);
        ps += p;
        Ps[w * 16 + lq * 4 + r][nt * 16 + l15] = f2bf(p);
      }
#pragma unroll
      for (int off = 1; off < 16; off <<= 1) ps += __shfl_xor(ps, off);
      l[r] = l[r] * sc + ps;
#pragma unroll
      for (int nt = 0; nt < 4; ++nt) oa[nt][r] *= sc;
    }

#pragma unroll
    for (int kk = 0; kk < 2; ++kk) {
      short8 pa = *(const short8*)&Ps[w * 16 + l15][kk * 32 + lq * 8];
      short8 vf[4];
#pragma unroll
      for (int nt = 0; nt < 4; ++nt) vf[nt] = ldsFrag(Vs, nt * 16 + l15, kk * 32 + lq * 8);
#pragma unroll
      for (int nt = 0; nt < 4; ++nt)
        oa[nt] = __builtin_amdgcn_mfma_f32_16x16x32_bf16(pa, vf[nt], oa[nt], 0, 0, 0);
    }
  }

  u16* obase = o + (size_t)(b * cfg::T + q0 + w * 16) * cfg::D + h * 64;
#pragma unroll
  for (int r = 0; r < 4; ++r) {
    const float inv = 1.f / l[r];
    const int rl = lq * 4 + r;
#pragma unroll
    for (int nt = 0; nt < 4; ++nt)
      obase[(size_t)rl * cfg::D + nt * 16 + l15] = f2bf(oa[nt][r] * inv);
  }
}

// ---------------- bf16 MFMA GEMM: 128xBN, BK=64, single-buffer (split-K paths) ----------------
template <int BN, int EPI, int OUTF32, int SWZ, int MMAJOR>
__launch_bounds__(256, 4)
__global__ void gemm_kernel(const u16* __restrict__ A, const u16* __restrict__ Bw,
                            const float* __restrict__ bias, void* __restrict__ Cp,
                            int lda, int ldb, int ldc, int K, long long partStride) {
  constexpr int BM = 128, BK = 64;
  constexpr int WN = BN / 2;
  constexpr int MF = 4, NF = WN / 16;
  int bx = blockIdx.x, by = blockIdx.y;
  if (SWZ) {
    const int gx = gridDim.x;
    const int nwg = gx * gridDim.y;
    const int lid = by * gx + bx;
    const int q = nwg >> 3, r = nwg & 7;
    const int xcd = lid & 7, rest = lid >> 3;
    const int nid = (xcd < r ? xcd * (q + 1) : r * (q + 1) + (xcd - r) * q) + rest;
    bx = nid % gx; by = nid / gx;
  }
  const int z = blockIdx.z;
  const u16* Ab = A + (size_t)z * K;
  const u16* Bb = Bw + (size_t)z * K;
  const int tid = threadIdx.x;
  const int lane = tid & 63;
  const int wid = tid >> 6;
  const int wr = wid >> 1, wc = wid & 1;
  const int m0 = (MMAJOR ? bx : by) * BM;
  const int n0 = (MMAJOR ? by : bx) * BN;

  __shared__ u16 As[BM][BK];
  __shared__ u16 Bs[BN][BK];

  const int nkt = K / BK;

  f32x4 acc[MF][NF];
#pragma unroll
  for (int i = 0; i < MF; ++i)
#pragma unroll
    for (int j = 0; j < NF; ++j) {
      acc[i][j][0] = 0.f; acc[i][j][1] = 0.f; acc[i][j][2] = 0.f; acc[i][j][3] = 0.f;
    }

  for (int kt = 0; kt < nkt; ++kt) {
    __syncthreads();
    const int kb = kt * BK;
    stageTile<(BM * BK) / 8>(&As[0][0], Ab + (size_t)m0 * lda + kb, lda, tid);
    stageTile<(BN * BK) / 8>(&Bs[0][0], Bb + (size_t)n0 * ldb + kb, ldb, tid);
    __syncthreads();
#pragma unroll
    for (int kk = 0; kk < BK / 32; ++kk) {
      short8 av[MF], bv[NF];
      const int kElem = kk * 32 + (lane >> 4) * 8;
#pragma unroll
      for (int mt = 0; mt < MF; ++mt)
        av[mt] = ldsFrag(&As[0][0], wr * 64 + mt * 16 + (lane & 15), kElem);
#pragma unroll
      for (int nt = 0; nt < NF; ++nt)
        bv[nt] = ldsFrag(&Bs[0][0], wc * WN + nt * 16 + (lane & 15), kElem);
#pragma unroll
      for (int mt = 0; mt < MF; ++mt)
#pragma unroll
        for (int nt = 0; nt < NF; ++nt)
          acc[mt][nt] = __builtin_amdgcn_mfma_f32_16x16x32_bf16(av[mt], bv[nt], acc[mt][nt], 0, 0, 0);
    }
  }

  const int rhi = (lane >> 4) * 4, cidx = lane & 15;
  const long long cb = (long long)z * partStride;
#pragma unroll
  for (int mt = 0; mt < MF; ++mt) {
#pragma unroll
    for (int nt = 0; nt < NF; ++nt) {
      const int col = n0 + wc * WN + nt * 16 + cidx;
      const float badd = bias ? bias[col] : 0.f;
#pragma unroll
      for (int r = 0; r < 4; ++r) {
        const int row = m0 + wr * 64 + mt * 16 + rhi + r;
        float val = acc[mt][nt][r] + badd;
        if (EPI == 1) {
          const float zz = 1.5957691216057308f * (val + 0.044715f * val * val * val);
          const float th = 1.f - 2.f / (__expf(zz) + 1.f);
          val = 0.5f * val * (1.f + th);
        }
        const size_t off = (size_t)(cb + (long long)row * ldc + col);
        if (OUTF32) ((float*)Cp)[off] = val;
        else ((u16*)Cp)[off] = f2bf(val);
      }
    }
  }
}

// ---------------- 128x64 deep-pipelined GEMM (QKV/FFN1): BK=32, 4 LDS bufs ----------------
// Same hazard ledger as gemm256c (R1-R3): 3-tile lookahead, 1 barrier/tile,
// counted vmcnt(6)/(3)/(0). 4 waves (2M x 2N), per-wave C = 64x32, 8 MFMA/tile.
// 48 KB static LDS -> 3 blocks/CU.
template <int EPI>
__launch_bounds__(256, 3)
__global__ void gemmdp_kernel(const u16* __restrict__ A, const u16* __restrict__ Bw,
                              const float* __restrict__ bias, u16* __restrict__ Cp,
                              int lda, int ldb, int ldc, int K) {
  __shared__ u16 lds[4 * 6144];   // buf: A 128x32 (4096) + B 64x32 (2048)
  const int tid = threadIdx.x;
  const int lane = tid & 63;
  const int wid = tid >> 6;
  const int wr = wid >> 1, wc = wid & 1;
  const int m0 = blockIdx.y * 128;
  const int n0 = blockIdx.x * 64;
  const int l15 = lane & 15, lq = lane >> 4;

  const u16* Abase = A + (size_t)m0 * lda;
  const u16* Bbase = Bw + (size_t)n0 * ldb;

  auto stage = [&](int buf, int kb) {   // 3 loads/thread: A x2, B x1
#pragma unroll
    for (int c = 0; c < 2; ++c) {
      const int ci = c * 256 + tid;
      const int r = ci >> 2;
      const int sc = (ci & 3) ^ ((r >> 1) & 3);
      gload16(lds + buf * 6144 + (size_t)ci * 8, Abase + (size_t)r * lda + kb + sc * 8);
    }
    {
      const int ci = tid;
      const int r = ci >> 2;
      const int sc = (ci & 3) ^ ((r >> 1) & 3);
      gload16(lds + buf * 6144 + 4096 + (size_t)ci * 8, Bbase + (size_t)r * ldb + kb + sc * 8);
    }
  };

  f32x4 acc[4][2];
#pragma unroll
  for (int i = 0; i < 4; ++i)
#pragma unroll
    for (int j = 0; j < 2; ++j) { acc[i][j][0] = 0.f; acc[i][j][1] = 0.f; acc[i][j][2] = 0.f; acc[i][j][3] = 0.f; }

  const int nt_ = K / 32;
  for (int t = 0; t < 3; ++t) stage(t, t * 32);   // prologue (K >= 96 always here)

  const int kE = lq * 8;
  for (int t = 0; t < nt_; ++t) {
    if (t < nt_ - 2) waitVm<6>();
    else if (t == nt_ - 2) waitVm<3>();
    else waitVm<0>();
    barrierRaw();                       // (R1) tile-t LDS globally visible
    const int buf = t & 3;
    const u16* At = lds + buf * 6144;
    const u16* Bt = lds + buf * 6144 + 4096;
    short8 av[4], bv[2];
#pragma unroll
    for (int mt = 0; mt < 4; ++mt)
      av[mt] = ldsFrag32(At, wr * 64 + mt * 16 + l15, kE);
#pragma unroll
    for (int nt = 0; nt < 2; ++nt)
      bv[nt] = ldsFrag32(Bt, wc * 32 + nt * 16 + l15, kE);
    if (t + 3 < nt_) stage((t + 3) & 3, (t + 3) * 32);   // (R2/R3) safe target
    waitLgkm0();
    __builtin_amdgcn_s_setprio(1);
#pragma unroll
    for (int mt = 0; mt < 4; ++mt)
#pragma unroll
      for (int nt = 0; nt < 2; ++nt)
        acc[mt][nt] = __builtin_amdgcn_mfma_f32_16x16x32_bf16(av[mt], bv[nt], acc[mt][nt], 0, 0, 0);
    __builtin_amdgcn_s_setprio(0);
  }

#pragma unroll
  for (int mt = 0; mt < 4; ++mt) {
#pragma unroll
    for (int nt = 0; nt < 2; ++nt) {
      const int col = n0 + wc * 32 + nt * 16 + l15;
      const float badd = bias[col];
#pragma unroll
      for (int r = 0; r < 4; ++r) {
        const int row = m0 + wr * 64 + mt * 16 + lq * 4 + r;
        float val = acc[mt][nt][r] + badd;
        if (EPI == 1) {
          const float zz = 1.5957691216057308f * (val + 0.044715f * val * val * val);
          const float th = 1.f - 2.f / (__expf(zz) + 1.f);
          val = 0.5f * val * (1.f + th);
        }
        Cp[(size_t)row * ldc + col] = f2bf(val);
      }
    }
  }
}

// ---------------- 256x256 deep-pipelined GEMM (logits): BK=32, 4 LDS buffers ----------------
// B-fragments hoisted out of the mh loop (read once per tile; were duplicated).
__launch_bounds__(512, 1)
__global__ void gemm256c_kernel(const u16* __restrict__ A, const u16* __restrict__ Bw,
                                const float* __restrict__ bias, float* __restrict__ Cp,
                                int lda, int ldb, int ldc, int K) {
  extern __shared__ u16 lds[];   // 4 bufs x (A 8192 + B 8192) u16 = 128 KB
  int bx = blockIdx.x, by = blockIdx.y;
  {  // bijective XCD swizzle; M-major (x = M-tiles share weight tile)
    const int gx = gridDim.x;
    const int nwg = gx * gridDim.y;
    const int lid = by * gx + bx;
    const int q = nwg >> 3, r = nwg & 7;
    const int xcd = lid & 7, rest = lid >> 3;
    const int nid = (xcd < r ? xcd * (q + 1) : r * (q + 1) + (xcd - r) * q) + rest;
    bx = nid % gx; by = nid / gx;
  }
  const int tid = threadIdx.x;
  const int lane = tid & 63;
  const int wid = tid >> 6;               // 0..7
  const int wr = wid >> 2, wc = wid & 3;  // 2M x 4N; per-wave C = 128x64
  const int m0 = bx * 256;
  const int n0 = by * 256;
  const int l15 = lane & 15, lq = lane >> 4;

  const u16* Abase = A + (size_t)m0 * lda;
  const u16* Bbase = Bw + (size_t)n0 * ldb;

  auto stageHalf = [&](int ldsOff, const u16* srcBase, int ld, int kb, int h) {
    const int ci = h * 512 + tid;
    const int r = ci >> 2;
    const int sc = (ci & 3) ^ ((r >> 1) & 3);
    gload16(lds + ldsOff + (size_t)ci * 8, srcBase + (size_t)r * ld + kb + sc * 8);
  };
  auto stageA = [&](int buf, int kb) {
    stageHalf(buf * 16384, Abase, lda, kb, 0);
    stageHalf(buf * 16384, Abase, lda, kb, 1);
  };
  auto stageB = [&](int buf, int kb) {
    stageHalf(buf * 16384 + 8192, Bbase, ldb, kb, 0);
    stageHalf(buf * 16384 + 8192, Bbase, ldb, kb, 1);
  };

  f32x4 acc[8][4];
#pragma unroll
  for (int i = 0; i < 8; ++i)
#pragma unroll
    for (int j = 0; j < 4; ++j) { acc[i][j][0] = 0.f; acc[i][j][1] = 0.f; acc[i][j][2] = 0.f; acc[i][j][3] = 0.f; }

  const int nt_ = K / 32;    // 32 tiles
  for (int t = 0; t < 3; ++t) { stageA(t, t * 32); stageB(t, t * 32); }

  const int kE = lq * 8;
  for (int t = 0; t < nt_; ++t) {
    if (t <= nt_ - 3) waitVm<8>();
    else if (t == nt_ - 2) waitVm<4>();
    else waitVm<0>();
    barrierRaw();
    const int buf = t & 3;
    const u16* At = lds + buf * 16384;
    const u16* Bt = lds + buf * 16384 + 8192;
    const int nbuf = (t + 3) & 3;
    const int kb3 = (t + 3) * 32;
    const bool pf = (t + 3 < nt_);
    short8 bv[4];
#pragma unroll
    for (int nt = 0; nt < 4; ++nt)
      bv[nt] = ldsFrag32(Bt, wc * 64 + nt * 16 + l15, kE);
#pragma unroll
    for (int mh = 0; mh < 2; ++mh) {
      short8 av[4];
#pragma unroll
      for (int mt = 0; mt < 4; ++mt)
        av[mt] = ldsFrag32(At, wr * 128 + mh * 64 + mt * 16 + l15, kE);
      if (pf) {
        if (mh == 0) stageA(nbuf, kb3);
        else stageB(nbuf, kb3);
      }
      waitLgkm0();
      __builtin_amdgcn_s_setprio(1);
#pragma unroll
      for (int mt = 0; mt < 4; ++mt)
#pragma unroll
        for (int nt = 0; nt < 4; ++nt)
          acc[mh * 4 + mt][nt] = __builtin_amdgcn_mfma_f32_16x16x32_bf16(av[mt], bv[nt], acc[mh * 4 + mt][nt], 0, 0, 0);
      __builtin_amdgcn_s_setprio(0);
    }
  }

#pragma unroll
  for (int g = 0; g < 8; ++g) {
#pragma unroll
    for (int nt = 0; nt < 4; ++nt) {
      const int col = n0 + wc * 64 + nt * 16 + l15;
      const float badd = bias[col];
#pragma unroll
      for (int r = 0; r < 4; ++r) {
        const int row = m0 + wr * 128 + g * 16 + lq * 4 + r;
        Cp[(size_t)row * ldc + col] = acc[g][nt][r] + badd;
      }
    }
  }
}

// ---------------- host ----------------
extern "C" void kernel_launch(void* const* d_in, const int* in_sizes, int n_in,
                              void* d_out, int out_size, void* d_ws, size_t ws_size,
                              hipStream_t stream) {
  using namespace cfg;
  (void)in_sizes; (void)n_in; (void)out_size;
  const int* x = (const int*)d_in[0];
  const float* tokW = (const float*)d_in[2];
  const float* pos = (const float*)d_in[3];
  const float* Wq = (const float*)d_in[4];  const float* bq = (const float*)d_in[5];
  const float* Wk = (const float*)d_in[6];  const float* bk = (const float*)d_in[7];
  const float* Wv = (const float*)d_in[8];  const float* bv = (const float*)d_in[9];
  const float* Wo = (const float*)d_in[10]; const float* bo = (const float*)d_in[11];
  const float* ln1g = (const float*)d_in[12]; const float* ln1b = (const float*)d_in[13];
  const float* W1 = (const float*)d_in[14]; const float* b1 = (const float*)d_in[15];
  const float* W2 = (const float*)d_in[16]; const float* b2 = (const float*)d_in[17];
  const float* ln2g = (const float*)d_in[18]; const float* ln2b = (const float*)d_in[19];
  const float* mWq = (const float*)d_in[20]; const float* mbq = (const float*)d_in[21];
  const float* mWk = (const float*)d_in[22]; const float* mbk = (const float*)d_in[23];
  const float* mWv = (const float*)d_in[24]; const float* mbv = (const float*)d_in[25];
  const float* mWo = (const float*)d_in[26]; const float* mbo = (const float*)d_in[27];
  const float* mlng = (const float*)d_in[28]; const float* mlnb = (const float*)d_in[29];
  const float* tWq = (const float*)d_in[30]; const float* tbq = (const float*)d_in[31];
  const float* tWk = (const float*)d_in[32]; const float* tbk = (const float*)d_in[33];
  const float* tWv = (const float*)d_in[34]; const float* tbv = (const float*)d_in[35];
  const float* tWo = (const float*)d_in[36]; const float* tbo = (const float*)d_in[37];
  const float* tlng = (const float*)d_in[38]; const float* tlnb = (const float*)d_in[39];
  const float* normg = (const float*)d_in[40]; const float* normb = (const float*)d_in[41];
  const float* outW = (const float*)d_in[42]; const float* outb = (const float*)d_in[43];

  const size_t DD = (size_t)D * D;
  const long long ND = (long long)N * D;
  char* wsb = (char*)d_ws;
  size_t off = 0;
  auto alloc = [&](size_t bytes) {
    void* p = wsb + off;
    off += (bytes + 255) & ~(size_t)255;
    return p;
  };
  u16* qkvW = (u16*)alloc((size_t)L * 3 * DD * 2);   // [L][3][D][D]
  u16* mqkvW = (u16*)alloc(3 * DD * 2);
  u16* tqkvW = (u16*)alloc(3 * DD * 2);
  u16* WoB = (u16*)alloc((size_t)L * DD * 2);
  u16* W1B = (u16*)alloc((size_t)L * F * D * 2);
  u16* W2B = (u16*)alloc((size_t)L * D * F * 2);
  u16* mWoB = (u16*)alloc(DD * 2);
  u16* tWoB = (u16*)alloc(DD * 2);
  u16* outWB = (u16*)alloc((size_t)V * D * 2);
  float* biasQKV = (float*)alloc((size_t)(L + 2) * 3 * D * 4);  // per-MHA concat [bq;bk;bv]
  float* hF = (float*)alloc((size_t)N * D * 4);
  u16* hB = (u16*)alloc((size_t)N * D * 2);
  float* pS = (float*)alloc((size_t)4 * N * D * 4);  // split-K partials (up to 4)
  u16* qkvB = (u16*)alloc((size_t)N * 3 * D * 2);
  u16* vtB = (u16*)alloc((size_t)N * D * 2);
  u16* oB = (u16*)alloc((size_t)N * D * 2);
  u16* f1B = (u16*)alloc((size_t)N * F * 2);
  if (off > ws_size) return;

  // ---- weight conversion fp32 -> bf16 (QKV interleaved per layer) ----
  CastArgs ca;
  int nj = 0; long total = 0;
  auto addJob = [&](const float* s, u16* dptr, size_t n) {
    ca.j[nj].src = s; ca.j[nj].dst = dptr; ca.j[nj].nBlk = (int)(n / 2048);
    total += (long)(n / 2048); ++nj;
  };
  for (int i = 0; i < L; ++i) {
    addJob(Wq + i * DD, qkvW + (size_t)i * 3 * DD, DD);
    addJob(Wk + i * DD, qkvW + (size_t)i * 3 * DD + DD, DD);
    addJob(Wv + i * DD, qkvW + (size_t)i * 3 * DD + 2 * DD, DD);
  }
  addJob(mWq, mqkvW, DD); addJob(mWk, mqkvW + DD, DD); addJob(mWv, mqkvW + 2 * DD, DD);
  addJob(tWq, tqkvW, DD); addJob(tWk, tqkvW + DD, DD); addJob(tWv, tqkvW + 2 * DD, DD);
  addJob(Wo, WoB, (size_t)L * DD);
  addJob(W1, W1B, (size_t)L * F * D);
  addJob(W2, W2B, (size_t)L * D * F);
  addJob(mWo, mWoB, DD); addJob(tWo, tWoB, DD);
  addJob(outW, outWB, (size_t)V * D);
  ca.n = nj;
  cast_kernel<<<dim3((unsigned)total), 256, 0, stream>>>(ca);

  // ---- bias concat ----
  CopyArgs cpa;
  int nc = 0;
  auto addCopy = [&](const float* s, float* dptr) { cpa.j[nc].src = s; cpa.j[nc].dst = dptr; ++nc; };
  for (int i = 0; i < L; ++i) {
    addCopy(bq + (size_t)i * D, biasQKV + (size_t)i * 3 * D);
    addCopy(bk + (size_t)i * D, biasQKV + (size_t)i * 3 * D + D);
    addCopy(bv + (size_t)i * D, biasQKV + (size_t)i * 3 * D + 2 * D);
  }
  addCopy(mbq, biasQKV + (size_t)L * 3 * D); addCopy(mbk, biasQKV + (size_t)L * 3 * D + D);
  addCopy(mbv, biasQKV + (size_t)L * 3 * D + 2 * D);
  addCopy(tbq, biasQKV + (size_t)(L + 1) * 3 * D); addCopy(tbk, biasQKV + (size_t)(L + 1) * 3 * D + D);
  addCopy(tbv, biasQKV + (size_t)(L + 1) * 3 * D + 2 * D);
  cpa.n = nc;
  bconcat_kernel<<<dim3((unsigned)nc), 256, 0, stream>>>(cpa);

  embed_kernel<<<N, 256, 0, stream>>>(x, tokW, pos, hF, hB);

  // MHA: QKV deep-pipelined (768 blk, 3/CU), attn, o-proj split-K=4 (1024 blk).
  auto mha = [&](const u16* qkvw, const float* qkvbias, const u16* wo) {
    gemmdp_kernel<0><<<dim3(3 * D / 64, N / 128, 1), 256, 0, stream>>>(
        hB, qkvw, qkvbias, qkvB, D, D, 3 * D, D);
    vtrans_kernel<<<dim3(T / 64, B * H), 256, 0, stream>>>(qkvB + 2 * D, vtB, 3 * D);
    fattn_kernel<<<dim3(T / 64, B * H), 256, 0, stream>>>(qkvB, vtB, oB);
    gemm_kernel<64, 0, 1, 0, 0><<<dim3(D / 64, N / 128, 4), 256, 0, stream>>>(
        oB, wo, nullptr, pS, D, D, D, 256, ND);
  };
  // LN after MHA: base + pS0..3 + o-proj bias
  auto lnMha = [&](const float* obias, const float* g, const float* b_) {
    ln_kernel<4><<<N, 256, 0, stream>>>(hF, pS, pS + ND, pS + 2 * ND, pS + 3 * ND,
                                        obias, g, b_, hF, hB);
  };

  int mi = 0;
  for (int i = 0; i < L; ++i) {
    mha(qkvW + (size_t)i * 3 * DD, biasQKV + (size_t)i * 3 * D, WoB + (size_t)i * DD);
    lnMha(bo + (size_t)i * D, ln1g + (size_t)i * D, ln1b + (size_t)i * D);
    // FFN1: deep-pipelined (1024 blk, 3/CU semantics) with fused GELU
    gemmdp_kernel<1><<<dim3(F / 64, N / 128, 1), 256, 0, stream>>>(
        hB, W1B + (size_t)i * F * D, b1 + (size_t)i * F, f1B, D, D, F, D);
    // FFN2: split-K=4 (K=4096 -> 4x1024), 1024 blocks
    gemm_kernel<64, 0, 1, 0, 0><<<dim3(D / 64, N / 128, 4), 256, 0, stream>>>(
        f1B, W2B + (size_t)i * D * F, nullptr, pS, F, F, D, 1024, ND);
    ln_kernel<4><<<N, 256, 0, stream>>>(hF, pS, pS + ND, pS + 2 * ND, pS + 3 * ND,
                                        b2 + (size_t)i * D, ln2g + (size_t)i * D,
                                        ln2b + (size_t)i * D, hF, hB);
    if (i % 3 == 2 && mi < 1) {
      mha(mqkvW, biasQKV + (size_t)L * 3 * D, mWoB);
      lnMha(mbo, mlng, mlnb);
      ++mi;
    }
  }
  // thought attention
  mha(tqkvW, biasQKV + (size_t)(L + 1) * 3 * D, tWoB);
  lnMha(tbo, tlng, tlnb);
  ln_kernel<0><<<N, 256, 0, stream>>>(hF, nullptr, nullptr, nullptr, nullptr, nullptr,
                                      normg, normb, hF, hB);

  // logits: deep-pipelined 256x256 (128 KB dynamic LDS); fallback = measured 128x128.
  hipError_t e = hipFuncSetAttribute(
      reinterpret_cast<const void*>(gemm256c_kernel),
      hipFuncAttributeMaxDynamicSharedMemorySize, 131072);
  if (e == hipSuccess) {
    gemm256c_kernel<<<dim3(N / 256, V / 256, 1), 512, 131072, stream>>>(
        hB, outWB, outb, (float*)d_out, D, D, V, D);
  } else {
    gemm_kernel<128, 0, 1, 1, 1><<<dim3(N / 128, V / 128, 1), 256, 0, stream>>>(
        hB, outWB, outb, (float*)d_out, D, D, V, D, 0);
  }
}

// Round 17
// 903.212 us; speedup vs baseline: 1.0318x; 1.0318x over previous
//
#include <hip/hip_runtime.h>
#include <cstdint>

#define DEV static __device__ __forceinline__

typedef unsigned short u16;
typedef __attribute__((ext_vector_type(8))) short short8;
typedef __attribute__((ext_vector_type(4))) float f32x4;

namespace cfg {
constexpr int V = 32000, D = 1024, H = 16, F = 4096, L = 3, T = 1024, B = 2;
constexpr int N = B * T;     // 2048 token rows
constexpr int HD = D / H;    // 64
}

DEV float bf2f(u16 b) { union { unsigned u; float f; } x; x.u = (unsigned)b << 16; return x.f; }
DEV u16 f2bf(float f) {
  union { float f; unsigned u; } x; x.f = f;
  unsigned u = x.u;
  return (u16)((u + 0x7fffu + ((u >> 16) & 1u)) >> 16);
}

DEV void gload16(void* lds, const void* g) {
  __builtin_amdgcn_global_load_lds((__attribute__((address_space(1))) void*)g,
                                   (__attribute__((address_space(3))) void*)lds, 16, 0, 0);
}

template <int NW>
DEV void waitVm() {
  if constexpr (NW == 0) asm volatile("s_waitcnt vmcnt(0)" ::: "memory");
  else if constexpr (NW == 4) asm volatile("s_waitcnt vmcnt(4)" ::: "memory");
  else if constexpr (NW == 8) asm volatile("s_waitcnt vmcnt(8)" ::: "memory");
  __builtin_amdgcn_sched_barrier(0);
}
DEV void barrierRaw() {
  __builtin_amdgcn_sched_barrier(0);
  __builtin_amdgcn_s_barrier();
  __builtin_amdgcn_sched_barrier(0);
}
DEV void waitLgkm0() {
  asm volatile("s_waitcnt lgkmcnt(0)" ::: "memory");
  __builtin_amdgcn_sched_barrier(0);
}

DEV float waveSum(float v) {
#pragma unroll
  for (int o = 32; o; o >>= 1) v += __shfl_xor(v, o);
  return v;
}

// ---------------- weight fp32 -> bf16 cast (batched jobs) ----------------
struct CastJob { const float* src; u16* dst; int nBlk; };
struct CastArgs { CastJob j[24]; int n; };

__global__ void cast_kernel(CastArgs a) {
  int blk = blockIdx.x;
  int i = 0;
  while (i + 1 < a.n && blk >= a.j[i].nBlk) { blk -= a.j[i].nBlk; ++i; }
  const size_t base = (size_t)blk * 2048 + threadIdx.x * 8;
  const float4* s4 = (const float4*)(a.j[i].src + base);
  const float4 v0 = s4[0], v1 = s4[1];
  short8 o;
  o[0] = (short)f2bf(v0.x); o[1] = (short)f2bf(v0.y);
  o[2] = (short)f2bf(v0.z); o[3] = (short)f2bf(v0.w);
  o[4] = (short)f2bf(v1.x); o[5] = (short)f2bf(v1.y);
  o[6] = (short)f2bf(v1.z); o[7] = (short)f2bf(v1.w);
  *(short8*)(a.j[i].dst + base) = o;
}

// ---------------- small fp32 copy (bias concat) ----------------
struct CopyJob { const float* src; float* dst; };
struct CopyArgs { CopyJob j[16]; int n; };
__global__ void bconcat_kernel(CopyArgs a) {
  const CopyJob jb = a.j[blockIdx.x];
  ((float4*)jb.dst)[threadIdx.x] = ((const float4*)jb.src)[threadIdx.x];
}

// ---------------- embedding: h = tok_W[x] + pos ----------------
__global__ void embed_kernel(const int* __restrict__ x, const float* __restrict__ tokW,
                             const float* __restrict__ pos, float* __restrict__ hF,
                             u16* __restrict__ hB) {
  const int bt = blockIdx.x;
  const int t = bt & (cfg::T - 1);
  const int tid = threadIdx.x;
  const int idx = x[bt];
  float4 v = ((const float4*)(tokW + (size_t)idx * cfg::D))[tid];
  const float4 p = ((const float4*)(pos + (size_t)t * cfg::D))[tid];
  v.x += p.x; v.y += p.y; v.z += p.z; v.w += p.w;
  ((float4*)(hF + (size_t)bt * cfg::D))[tid] = v;
  union { u16 u[4]; uint2 q; } pk;
  pk.u[0] = f2bf(v.x); pk.u[1] = f2bf(v.y); pk.u[2] = f2bf(v.z); pk.u[3] = f2bf(v.w);
  *(uint2*)(hB + (size_t)bt * cfg::D + tid * 4) = pk.q;
}

// ---------------- residual + (sum of NADD split-K partials) + bias + LayerNorm ----------------
template <int NADD>
__global__ void ln_kernel(const float* __restrict__ base,
                          const float* __restrict__ a0, const float* __restrict__ a1,
                          const float* __restrict__ a2, const float* __restrict__ a3,
                          const float* __restrict__ biasv,
                          const float* __restrict__ g, const float* __restrict__ bt,
                          float* __restrict__ outF, u16* __restrict__ outB) {
  const int row = blockIdx.x, tid = threadIdx.x;
  const int lane = tid & 63, wid = tid >> 6;
  const size_t roff = (size_t)row * cfg::D;
  float4 x = ((const float4*)(base + roff))[tid];
  if (NADD >= 1) {
    const float4 a = ((const float4*)(a0 + roff))[tid];
    x.x += a.x; x.y += a.y; x.z += a.z; x.w += a.w;
  }
  if (NADD >= 2) {
    const float4 a = ((const float4*)(a1 + roff))[tid];
    x.x += a.x; x.y += a.y; x.z += a.z; x.w += a.w;
  }
  if (NADD >= 3) {
    const float4 a = ((const float4*)(a2 + roff))[tid];
    x.x += a.x; x.y += a.y; x.z += a.z; x.w += a.w;
  }
  if (NADD >= 4) {
    const float4 a = ((const float4*)(a3 + roff))[tid];
    x.x += a.x; x.y += a.y; x.z += a.z; x.w += a.w;
  }
  if (biasv) {
    const float4 a = ((const float4*)biasv)[tid];
    x.x += a.x; x.y += a.y; x.z += a.z; x.w += a.w;
  }
  float s = x.x + x.y + x.z + x.w;
  float s2 = x.x * x.x + x.y * x.y + x.z * x.z + x.w * x.w;
  __shared__ float sb[8];
  s = waveSum(s); s2 = waveSum(s2);
  if (lane == 0) { sb[wid] = s; sb[4 + wid] = s2; }
  __syncthreads();
  s = sb[0] + sb[1] + sb[2] + sb[3];
  s2 = sb[4] + sb[5] + sb[6] + sb[7];
  const float mean = s * (1.f / cfg::D);
  const float rs = rsqrtf(s2 * (1.f / cfg::D) - mean * mean + 1e-5f);
  const float4 gv = ((const float4*)g)[tid];
  const float4 bv = ((const float4*)bt)[tid];
  float4 y;
  y.x = (x.x - mean) * rs * gv.x + bv.x;
  y.y = (x.y - mean) * rs * gv.y + bv.y;
  y.z = (x.z - mean) * rs * gv.z + bv.z;
  y.w = (x.w - mean) * rs * gv.w + bv.w;
  ((float4*)(outF + roff))[tid] = y;
  union { u16 u[4]; uint2 q; } pk;
  pk.u[0] = f2bf(y.x); pk.u[1] = f2bf(y.y); pk.u[2] = f2bf(y.z); pk.u[3] = f2bf(y.w);
  *(uint2*)(outB + roff + tid * 4) = pk.q;
}

// ---------------- V transpose: picks v-slice, [B,T,D3]->[B*H, HD, T] ----------------
__global__ void vtrans_kernel(const u16* __restrict__ v, u16* __restrict__ vtO, int vstride) {
  __shared__ u16 s[64][68];
  const int bh = blockIdx.y, b = bh >> 4, h = bh & 15;
  const int t0 = blockIdx.x * 64;
  const int tid = threadIdx.x;
  const int r2 = tid >> 3, cg = tid & 7;
#pragma unroll
  for (int p = 0; p < 2; ++p) {
    const int r = p * 32 + r2;
    const short8 val = *(const short8*)(v + (size_t)(b * cfg::T + t0 + r) * vstride + h * 64 + cg * 8);
#pragma unroll
    for (int j = 0; j < 8; ++j) s[r][cg * 8 + j] = (u16)val[j];
  }
  __syncthreads();
#pragma unroll
  for (int p = 0; p < 2; ++p) {
    const int d = p * 32 + r2;
    short8 o;
#pragma unroll
    for (int j = 0; j < 8; ++j) o[j] = (short)s[cg * 8 + j][d];
    *(short8*)(vtO + ((size_t)bh * 64 + d) * (size_t)cfg::T + t0 + cg * 8) = o;
  }
}

// ---------------- swizzled LDS staging, 128B rows ----------------
template <int NCH>
DEV void stageTile(u16* lds, const u16* src, int strideElems, int tid) {
#pragma unroll
  for (int c = 0; c < NCH / 256; ++c) {
    const int ci = c * 256 + tid;
    const int r = ci >> 3;
    const int c8 = ci & 7;
    const int sc8 = c8 ^ (r & 7);
    gload16(lds + (size_t)ci * 8, src + (size_t)r * strideElems + sc8 * 8);
  }
}
DEV short8 ldsFrag(const u16* tile, int row, int kElem) {
  const int byteoff = row * 128 + ((kElem * 2) ^ ((row & 7) << 4));
  return *(const short8*)((const char*)tile + byteoff);
}
// 64B rows (BK=32): residual 2-way bank aliasing only (free).
DEV short8 ldsFrag32(const u16* tile, int row, int kElem) {
  const int byteoff = row * 64 + ((kElem * 2) ^ (((row >> 1) & 3) << 4));
  return *(const short8*)((const char*)tile + byteoff);
}

// ---------------- flash attention: QBLK=64, grid (T/64, B*H), 256 thr ----------------
__launch_bounds__(256, 3)
__global__ void fattn_kernel(const u16* __restrict__ qkv, const u16* __restrict__ vt,
                             u16* __restrict__ o) {
  constexpr int D3 = 3 * cfg::D;
  __shared__ u16 Qs[64 * 64];
  __shared__ u16 Ks[64 * 64];
  __shared__ u16 Vs[64 * 64];
  __shared__ u16 Ps[64][72];
  const int tid = threadIdx.x, lane = tid & 63, w = tid >> 6;
  const int qt = gridDim.x - 1 - blockIdx.x;   // longest-first scheduling
  const int bh = blockIdx.y;
  const int b = bh >> 4, h = bh & 15;
  const int q0 = qt * 64;
  const int l15 = lane & 15, lq = lane >> 4;

  stageTile<512>(Qs, qkv + (size_t)(b * cfg::T + q0) * D3 + h * 64, D3, tid);
  __syncthreads();
  short8 qf[2];
#pragma unroll
  for (int kk = 0; kk < 2; ++kk)
    qf[kk] = ldsFrag(Qs, w * 16 + l15, kk * 32 + lq * 8);

  f32x4 oa[4];
  float m[4], l[4];
#pragma unroll
  for (int r = 0; r < 4; ++r) { m[r] = -1e30f; l[r] = 0.f; }
#pragma unroll
  for (int nt = 0; nt < 4; ++nt) { oa[nt][0] = 0; oa[nt][1] = 0; oa[nt][2] = 0; oa[nt][3] = 0; }

  const int nkt = qt + 1;
  const u16* kbase = qkv + (size_t)(b * cfg::T) * D3 + cfg::D + h * 64;
  const u16* vbase = vt + (size_t)bh * 64 * cfg::T;

  for (int kt = 0; kt < nkt; ++kt) {
    const int k0 = kt * 64;
    __syncthreads();
    stageTile<512>(Ks, kbase + (size_t)k0 * D3, D3, tid);
    stageTile<512>(Vs, vbase + k0, cfg::T, tid);
    __syncthreads();

    f32x4 sa[4];
#pragma unroll
    for (int nt = 0; nt < 4; ++nt) { sa[nt][0] = 0; sa[nt][1] = 0; sa[nt][2] = 0; sa[nt][3] = 0; }
#pragma unroll
    for (int kk = 0; kk < 2; ++kk) {
      short8 kf[4];
#pragma unroll
      for (int nt = 0; nt < 4; ++nt) kf[nt] = ldsFrag(Ks, nt * 16 + l15, kk * 32 + lq * 8);
#pragma unroll
      for (int nt = 0; nt < 4; ++nt)
        sa[nt] = __builtin_amdgcn_mfma_f32_16x16x32_bf16(qf[kk], kf[nt], sa[nt], 0, 0, 0);
    }

    const bool needMask = (kt >= qt);
#pragma unroll
    for (int r = 0; r < 4; ++r) {
      const int qrow = q0 + w * 16 + lq * 4 + r;
      float s[4];
#pragma unroll
      for (int nt = 0; nt < 4; ++nt) {
        s[nt] = sa[nt][r] * 0.125f;
        if (needMask && (k0 + nt * 16 + l15 > qrow)) s[nt] = -3e38f;
      }
      float rm = fmaxf(fmaxf(s[0], s[1]), fmaxf(s[2], s[3]));
#pragma unroll
      for (int off = 1; off < 16; off <<= 1) rm = fmaxf(rm, __shfl_xor(rm, off));
      const float mn = fmaxf(m[r], rm);
      const float sc = __expf(m[r] - mn);
      m[r] = mn;
      float ps = 0.f;
#pragma unroll
      for (int nt = 0; nt < 4; ++nt) {
        const float p = __expf(s[nt] - mn);
        ps += p;
        Ps[w * 16 + lq * 4 + r][nt * 16 + l15] = f2bf(p);
      }
#pragma unroll
      for (int off = 1; off < 16; off <<= 1) ps += __shfl_xor(ps, off);
      l[r] = l[r] * sc + ps;
#pragma unroll
      for (int nt = 0; nt < 4; ++nt) oa[nt][r] *= sc;
    }

#pragma unroll
    for (int kk = 0; kk < 2; ++kk) {
      short8 pa = *(const short8*)&Ps[w * 16 + l15][kk * 32 + lq * 8];
      short8 vf[4];
#pragma unroll
      for (int nt = 0; nt < 4; ++nt) vf[nt] = ldsFrag(Vs, nt * 16 + l15, kk * 32 + lq * 8);
#pragma unroll
      for (int nt = 0; nt < 4; ++nt)
        oa[nt] = __builtin_amdgcn_mfma_f32_16x16x32_bf16(pa, vf[nt], oa[nt], 0, 0, 0);
    }
  }

  u16* obase = o + (size_t)(b * cfg::T + q0 + w * 16) * cfg::D + h * 64;
#pragma unroll
  for (int r = 0; r < 4; ++r) {
    const float inv = 1.f / l[r];
    const int rl = lq * 4 + r;
#pragma unroll
    for (int nt = 0; nt < 4; ++nt)
      obase[(size_t)rl * cfg::D + nt * 16 + l15] = f2bf(oa[nt][r] * inv);
  }
}

// ---------------- bf16 MFMA GEMM: 128xBN, BK=64, single-buffer ----------------
// Split-K via blockIdx.z: K param is the per-split K; A/B column offset z*K,
// C written to Cp + z*partStride (no bias on split paths; summed in ln_kernel).
template <int BN, int EPI, int OUTF32, int SWZ, int MMAJOR>
__launch_bounds__(256, 4)
__global__ void gemm_kernel(const u16* __restrict__ A, const u16* __restrict__ Bw,
                            const float* __restrict__ bias, void* __restrict__ Cp,
                            int lda, int ldb, int ldc, int K, long long partStride) {
  constexpr int BM = 128, BK = 64;
  constexpr int WN = BN / 2;
  constexpr int MF = 4, NF = WN / 16;
  int bx = blockIdx.x, by = blockIdx.y;
  if (SWZ) {
    const int gx = gridDim.x;
    const int nwg = gx * gridDim.y;
    const int lid = by * gx + bx;
    const int q = nwg >> 3, r = nwg & 7;
    const int xcd = lid & 7, rest = lid >> 3;
    const int nid = (xcd < r ? xcd * (q + 1) : r * (q + 1) + (xcd - r) * q) + rest;
    bx = nid % gx; by = nid / gx;
  }
  const int z = blockIdx.z;
  const u16* Ab = A + (size_t)z * K;
  const u16* Bb = Bw + (size_t)z * K;
  const int tid = threadIdx.x;
  const int lane = tid & 63;
  const int wid = tid >> 6;
  const int wr = wid >> 1, wc = wid & 1;
  const int m0 = (MMAJOR ? bx : by) * BM;
  const int n0 = (MMAJOR ? by : bx) * BN;

  __shared__ u16 As[BM][BK];
  __shared__ u16 Bs[BN][BK];

  const int nkt = K / BK;

  f32x4 acc[MF][NF];
#pragma unroll
  for (int i = 0; i < MF; ++i)
#pragma unroll
    for (int j = 0; j < NF; ++j) {
      acc[i][j][0] = 0.f; acc[i][j][1] = 0.f; acc[i][j][2] = 0.f; acc[i][j][3] = 0.f;
    }

  for (int kt = 0; kt < nkt; ++kt) {
    __syncthreads();
    const int kb = kt * BK;
    stageTile<(BM * BK) / 8>(&As[0][0], Ab + (size_t)m0 * lda + kb, lda, tid);
    stageTile<(BN * BK) / 8>(&Bs[0][0], Bb + (size_t)n0 * ldb + kb, ldb, tid);
    __syncthreads();
#pragma unroll
    for (int kk = 0; kk < BK / 32; ++kk) {
      short8 av[MF], bv[NF];
      const int kElem = kk * 32 + (lane >> 4) * 8;
#pragma unroll
      for (int mt = 0; mt < MF; ++mt)
        av[mt] = ldsFrag(&As[0][0], wr * 64 + mt * 16 + (lane & 15), kElem);
#pragma unroll
      for (int nt = 0; nt < NF; ++nt)
        bv[nt] = ldsFrag(&Bs[0][0], wc * WN + nt * 16 + (lane & 15), kElem);
#pragma unroll
      for (int mt = 0; mt < MF; ++mt)
#pragma unroll
        for (int nt = 0; nt < NF; ++nt)
          acc[mt][nt] = __builtin_amdgcn_mfma_f32_16x16x32_bf16(av[mt], bv[nt], acc[mt][nt], 0, 0, 0);
    }
  }

  const int rhi = (lane >> 4) * 4, cidx = lane & 15;
  const long long cb = (long long)z * partStride;
#pragma unroll
  for (int mt = 0; mt < MF; ++mt) {
#pragma unroll
    for (int nt = 0; nt < NF; ++nt) {
      const int col = n0 + wc * WN + nt * 16 + cidx;
      const float badd = bias ? bias[col] : 0.f;
#pragma unroll
      for (int r = 0; r < 4; ++r) {
        const int row = m0 + wr * 64 + mt * 16 + rhi + r;
        float val = acc[mt][nt][r] + badd;
        if (EPI == 1) {
          const float zz = 1.5957691216057308f * (val + 0.044715f * val * val * val);
          const float th = 1.f - 2.f / (__expf(zz) + 1.f);
          val = 0.5f * val * (1.f + th);
        }
        const size_t off = (size_t)(cb + (long long)row * ldc + col);
        if (OUTF32) ((float*)Cp)[off] = val;
        else ((u16*)Cp)[off] = f2bf(val);
      }
    }
  }
}

// ---------------- 256x256 deep-pipelined GEMM (logits): BK=32, 4 LDS buffers ----------------
// 3-tile lookahead, ONE barrier per tile, counted vmcnt ladder, B-frags hoisted.
// Hazard ledger: (R1) wait->barrier makes tile-t LDS globally visible;
// (R2) stage of t+3 targets buf (t-1)&3 whose reads drained pre-barrier;
// (R3) buf t&3 never written during tile t.
__launch_bounds__(512, 1)
__global__ void gemm256c_kernel(const u16* __restrict__ A, const u16* __restrict__ Bw,
                                const float* __restrict__ bias, float* __restrict__ Cp,
                                int lda, int ldb, int ldc, int K) {
  extern __shared__ u16 lds[];   // 4 bufs x (A 8192 + B 8192) u16 = 128 KB
  int bx = blockIdx.x, by = blockIdx.y;
  {  // bijective XCD swizzle; M-major (x = M-tiles share weight tile)
    const int gx = gridDim.x;
    const int nwg = gx * gridDim.y;
    const int lid = by * gx + bx;
    const int q = nwg >> 3, r = nwg & 7;
    const int xcd = lid & 7, rest = lid >> 3;
    const int nid = (xcd < r ? xcd * (q + 1) : r * (q + 1) + (xcd - r) * q) + rest;
    bx = nid % gx; by = nid / gx;
  }
  const int tid = threadIdx.x;
  const int lane = tid & 63;
  const int wid = tid >> 6;               // 0..7
  const int wr = wid >> 2, wc = wid & 3;  // 2M x 4N; per-wave C = 128x64
  const int m0 = bx * 256;
  const int n0 = by * 256;
  const int l15 = lane & 15, lq = lane >> 4;

  const u16* Abase = A + (size_t)m0 * lda;
  const u16* Bbase = Bw + (size_t)n0 * ldb;

  auto stageHalf = [&](int ldsOff, const u16* srcBase, int ld, int kb, int h) {
    const int ci = h * 512 + tid;
    const int r = ci >> 2;
    const int sc = (ci & 3) ^ ((r >> 1) & 3);
    gload16(lds + ldsOff + (size_t)ci * 8, srcBase + (size_t)r * ld + kb + sc * 8);
  };
  auto stageA = [&](int buf, int kb) {
    stageHalf(buf * 16384, Abase, lda, kb, 0);
    stageHalf(buf * 16384, Abase, lda, kb, 1);
  };
  auto stageB = [&](int buf, int kb) {
    stageHalf(buf * 16384 + 8192, Bbase, ldb, kb, 0);
    stageHalf(buf * 16384 + 8192, Bbase, ldb, kb, 1);
  };

  f32x4 acc[8][4];
#pragma unroll
  for (int i = 0; i < 8; ++i)
#pragma unroll
    for (int j = 0; j < 4; ++j) { acc[i][j][0] = 0.f; acc[i][j][1] = 0.f; acc[i][j][2] = 0.f; acc[i][j][3] = 0.f; }

  const int nt_ = K / 32;    // 32 tiles
  for (int t = 0; t < 3; ++t) { stageA(t, t * 32); stageB(t, t * 32); }

  const int kE = lq * 8;
  for (int t = 0; t < nt_; ++t) {
    if (t <= nt_ - 3) waitVm<8>();
    else if (t == nt_ - 2) waitVm<4>();
    else waitVm<0>();
    barrierRaw();
    const int buf = t & 3;
    const u16* At = lds + buf * 16384;
    const u16* Bt = lds + buf * 16384 + 8192;
    const int nbuf = (t + 3) & 3;
    const int kb3 = (t + 3) * 32;
    const bool pf = (t + 3 < nt_);
    short8 bv[4];
#pragma unroll
    for (int nt = 0; nt < 4; ++nt)
      bv[nt] = ldsFrag32(Bt, wc * 64 + nt * 16 + l15, kE);
#pragma unroll
    for (int mh = 0; mh < 2; ++mh) {
      short8 av[4];
#pragma unroll
      for (int mt = 0; mt < 4; ++mt)
        av[mt] = ldsFrag32(At, wr * 128 + mh * 64 + mt * 16 + l15, kE);
      if (pf) {
        if (mh == 0) stageA(nbuf, kb3);
        else stageB(nbuf, kb3);
      }
      waitLgkm0();
      __builtin_amdgcn_s_setprio(1);
#pragma unroll
      for (int mt = 0; mt < 4; ++mt)
#pragma unroll
        for (int nt = 0; nt < 4; ++nt)
          acc[mh * 4 + mt][nt] = __builtin_amdgcn_mfma_f32_16x16x32_bf16(av[mt], bv[nt], acc[mh * 4 + mt][nt], 0, 0, 0);
      __builtin_amdgcn_s_setprio(0);
    }
  }

#pragma unroll
  for (int g = 0; g < 8; ++g) {
#pragma unroll
    for (int nt = 0; nt < 4; ++nt) {
      const int col = n0 + wc * 64 + nt * 16 + l15;
      const float badd = bias[col];
#pragma unroll
      for (int r = 0; r < 4; ++r) {
        const int row = m0 + wr * 128 + g * 16 + lq * 4 + r;
        Cp[(size_t)row * ldc + col] = acc[g][nt][r] + badd;
      }
    }
  }
}

// ---------------- host ----------------
extern "C" void kernel_launch(void* const* d_in, const int* in_sizes, int n_in,
                              void* d_out, int out_size, void* d_ws, size_t ws_size,
                              hipStream_t stream) {
  using namespace cfg;
  (void)in_sizes; (void)n_in; (void)out_size;
  const int* x = (const int*)d_in[0];
  const float* tokW = (const float*)d_in[2];
  const float* pos = (const float*)d_in[3];
  const float* Wq = (const float*)d_in[4];  const float* bq = (const float*)d_in[5];
  const float* Wk = (const float*)d_in[6];  const float* bk = (const float*)d_in[7];
  const float* Wv = (const float*)d_in[8];  const float* bv = (const float*)d_in[9];
  const float* Wo = (const float*)d_in[10]; const float* bo = (const float*)d_in[11];
  const float* ln1g = (const float*)d_in[12]; const float* ln1b = (const float*)d_in[13];
  const float* W1 = (const float*)d_in[14]; const float* b1 = (const float*)d_in[15];
  const float* W2 = (const float*)d_in[16]; const float* b2 = (const float*)d_in[17];
  const float* ln2g = (const float*)d_in[18]; const float* ln2b = (const float*)d_in[19];
  const float* mWq = (const float*)d_in[20]; const float* mbq = (const float*)d_in[21];
  const float* mWk = (const float*)d_in[22]; const float* mbk = (const float*)d_in[23];
  const float* mWv = (const float*)d_in[24]; const float* mbv = (const float*)d_in[25];
  const float* mWo = (const float*)d_in[26]; const float* mbo = (const float*)d_in[27];
  const float* mlng = (const float*)d_in[28]; const float* mlnb = (const float*)d_in[29];
  const float* tWq = (const float*)d_in[30]; const float* tbq = (const float*)d_in[31];
  const float* tWk = (const float*)d_in[32]; const float* tbk = (const float*)d_in[33];
  const float* tWv = (const float*)d_in[34]; const float* tbv = (const float*)d_in[35];
  const float* tWo = (const float*)d_in[36]; const float* tbo = (const float*)d_in[37];
  const float* tlng = (const float*)d_in[38]; const float* tlnb = (const float*)d_in[39];
  const float* normg = (const float*)d_in[40]; const float* normb = (const float*)d_in[41];
  const float* outW = (const float*)d_in[42]; const float* outb = (const float*)d_in[43];

  const size_t DD = (size_t)D * D;
  const long long ND = (long long)N * D;
  char* wsb = (char*)d_ws;
  size_t off = 0;
  auto alloc = [&](size_t bytes) {
    void* p = wsb + off;
    off += (bytes + 255) & ~(size_t)255;
    return p;
  };
  u16* qkvW = (u16*)alloc((size_t)L * 3 * DD * 2);   // [L][3][D][D]
  u16* mqkvW = (u16*)alloc(3 * DD * 2);
  u16* tqkvW = (u16*)alloc(3 * DD * 2);
  u16* WoB = (u16*)alloc((size_t)L * DD * 2);
  u16* W1B = (u16*)alloc((size_t)L * F * D * 2);
  u16* W2B = (u16*)alloc((size_t)L * D * F * 2);
  u16* mWoB = (u16*)alloc(DD * 2);
  u16* tWoB = (u16*)alloc(DD * 2);
  u16* outWB = (u16*)alloc((size_t)V * D * 2);
  float* biasQKV = (float*)alloc((size_t)(L + 2) * 3 * D * 4);  // per-MHA concat [bq;bk;bv]
  float* hF = (float*)alloc((size_t)N * D * 4);
  u16* hB = (u16*)alloc((size_t)N * D * 2);
  float* pS = (float*)alloc((size_t)4 * N * D * 4);  // split-K partials (up to 4)
  u16* qkvB = (u16*)alloc((size_t)N * 3 * D * 2);
  u16* vtB = (u16*)alloc((size_t)N * D * 2);
  u16* oB = (u16*)alloc((size_t)N * D * 2);
  u16* f1B = (u16*)alloc((size_t)N * F * 2);
  if (off > ws_size) return;

  // ---- weight conversion fp32 -> bf16 (QKV interleaved per layer) ----
  CastArgs ca;
  int nj = 0; long total = 0;
  auto addJob = [&](const float* s, u16* dptr, size_t n) {
    ca.j[nj].src = s; ca.j[nj].dst = dptr; ca.j[nj].nBlk = (int)(n / 2048);
    total += (long)(n / 2048); ++nj;
  };
  for (int i = 0; i < L; ++i) {
    addJob(Wq + i * DD, qkvW + (size_t)i * 3 * DD, DD);
    addJob(Wk + i * DD, qkvW + (size_t)i * 3 * DD + DD, DD);
    addJob(Wv + i * DD, qkvW + (size_t)i * 3 * DD + 2 * DD, DD);
  }
  addJob(mWq, mqkvW, DD); addJob(mWk, mqkvW + DD, DD); addJob(mWv, mqkvW + 2 * DD, DD);
  addJob(tWq, tqkvW, DD); addJob(tWk, tqkvW + DD, DD); addJob(tWv, tqkvW + 2 * DD, DD);
  addJob(Wo, WoB, (size_t)L * DD);
  addJob(W1, W1B, (size_t)L * F * D);
  addJob(W2, W2B, (size_t)L * D * F);
  addJob(mWo, mWoB, DD); addJob(tWo, tWoB, DD);
  addJob(outW, outWB, (size_t)V * D);
  ca.n = nj;
  cast_kernel<<<dim3((unsigned)total), 256, 0, stream>>>(ca);

  // ---- bias concat ----
  CopyArgs cpa;
  int nc = 0;
  auto addCopy = [&](const float* s, float* dptr) { cpa.j[nc].src = s; cpa.j[nc].dst = dptr; ++nc; };
  for (int i = 0; i < L; ++i) {
    addCopy(bq + (size_t)i * D, biasQKV + (size_t)i * 3 * D);
    addCopy(bk + (size_t)i * D, biasQKV + (size_t)i * 3 * D + D);
    addCopy(bv + (size_t)i * D, biasQKV + (size_t)i * 3 * D + 2 * D);
  }
  addCopy(mbq, biasQKV + (size_t)L * 3 * D); addCopy(mbk, biasQKV + (size_t)L * 3 * D + D);
  addCopy(mbv, biasQKV + (size_t)L * 3 * D + 2 * D);
  addCopy(tbq, biasQKV + (size_t)(L + 1) * 3 * D); addCopy(tbk, biasQKV + (size_t)(L + 1) * 3 * D + D);
  addCopy(tbv, biasQKV + (size_t)(L + 1) * 3 * D + 2 * D);
  cpa.n = nc;
  bconcat_kernel<<<dim3((unsigned)nc), 256, 0, stream>>>(cpa);

  embed_kernel<<<N, 256, 0, stream>>>(x, tokW, pos, hF, hB);

  // MHA: QKV (BN=64, 768 blk), attn, then o-proj split-K=4 into pS[0..3] (1024 blk).
  auto mha = [&](const u16* qkvw, const float* qkvbias, const u16* wo) {
    gemm_kernel<64, 0, 0, 0, 0><<<dim3(3 * D / 64, N / 128, 1), 256, 0, stream>>>(
        hB, qkvw, qkvbias, qkvB, D, D, 3 * D, D, 0);
    vtrans_kernel<<<dim3(T / 64, B * H), 256, 0, stream>>>(qkvB + 2 * D, vtB, 3 * D);
    fattn_kernel<<<dim3(T / 64, B * H), 256, 0, stream>>>(qkvB, vtB, oB);
    gemm_kernel<64, 0, 1, 0, 0><<<dim3(D / 64, N / 128, 4), 256, 0, stream>>>(
        oB, wo, nullptr, pS, D, D, D, 256, ND);
  };
  // LN after MHA: base + pS0..3 + o-proj bias
  auto lnMha = [&](const float* obias, const float* g, const float* b_) {
    ln_kernel<4><<<N, 256, 0, stream>>>(hF, pS, pS + ND, pS + 2 * ND, pS + 3 * ND,
                                        obias, g, b_, hF, hB);
  };

  int mi = 0;
  for (int i = 0; i < L; ++i) {
    mha(qkvW + (size_t)i * 3 * DD, biasQKV + (size_t)i * 3 * D, WoB + (size_t)i * DD);
    lnMha(bo + (size_t)i * D, ln1g + (size_t)i * D, ln1b + (size_t)i * D);
    gemm_kernel<64, 1, 0, 0, 0><<<dim3(F / 64, N / 128, 1), 256, 0, stream>>>(
        hB, W1B + (size_t)i * F * D, b1 + (size_t)i * F, f1B, D, D, F, D, 0);
    // FFN2: split-K=4 (K=4096 -> 4x1024), 1024 blocks
    gemm_kernel<64, 0, 1, 0, 0><<<dim3(D / 64, N / 128, 4), 256, 0, stream>>>(
        f1B, W2B + (size_t)i * D * F, nullptr, pS, F, F, D, 1024, ND);
    ln_kernel<4><<<N, 256, 0, stream>>>(hF, pS, pS + ND, pS + 2 * ND, pS + 3 * ND,
                                        b2 + (size_t)i * D, ln2g + (size_t)i * D,
                                        ln2b + (size_t)i * D, hF, hB);
    if (i % 3 == 2 && mi < 1) {
      mha(mqkvW, biasQKV + (size_t)L * 3 * D, mWoB);
      lnMha(mbo, mlng, mlnb);
      ++mi;
    }
  }
  // thought attention
  mha(tqkvW, biasQKV + (size_t)(L + 1) * 3 * D, tWoB);
  lnMha(tbo, tlng, tlnb);
  ln_kernel<0><<<N, 256, 0, stream>>>(hF, nullptr, nullptr, nullptr, nullptr, nullptr,
                                      normg, normb, hF, hB);

  // logits: deep-pipelined 256x256 (128 KB dynamic LDS); fallback = measured 128x128.
  hipError_t e = hipFuncSetAttribute(
      reinterpret_cast<const void*>(gemm256c_kernel),
      hipFuncAttributeMaxDynamicSharedMemorySize, 131072);
  if (e == hipSuccess) {
    gemm256c_kernel<<<dim3(N / 256, V / 256, 1), 512, 131072, stream>>>(
        hB, outWB, outb, (float*)d_out, D, D, V, D);
  } else {
    gemm_kernel<128, 0, 1, 1, 1><<<dim3(N / 128, V / 128, 1), 256, 0, stream>>>(
        hB, outWB, outb, (float*)d_out, D, D, V, D, 0);
  }
}

// Round 18
// 870.266 us; speedup vs baseline: 1.0709x; 1.0379x over previous
//
#include <hip/hip_runtime.h>
#include <cstdint>

#define DEV static __device__ __forceinline__

typedef unsigned short u16;
typedef __attribute__((ext_vector_type(8))) short short8;
typedef __attribute__((ext_vector_type(4))) float f32x4;

namespace cfg {
constexpr int V = 32000, D = 1024, H = 16, F = 4096, L = 3, T = 1024, B = 2;
constexpr int N = B * T;     // 2048 token rows
constexpr int HD = D / H;    // 64
}

DEV float bf2f(u16 b) { union { unsigned u; float f; } x; x.u = (unsigned)b << 16; return x.f; }
DEV u16 f2bf(float f) {
  union { float f; unsigned u; } x; x.f = f;
  unsigned u = x.u;
  return (u16)((u + 0x7fffu + ((u >> 16) & 1u)) >> 16);
}

DEV void gload16(void* lds, const void* g) {
  __builtin_amdgcn_global_load_lds((__attribute__((address_space(1))) void*)g,
                                   (__attribute__((address_space(3))) void*)lds, 16, 0, 0);
}

template <int NW>
DEV void waitVm() {
  if constexpr (NW == 0) asm volatile("s_waitcnt vmcnt(0)" ::: "memory");
  else if constexpr (NW == 4) asm volatile("s_waitcnt vmcnt(4)" ::: "memory");
  else if constexpr (NW == 8) asm volatile("s_waitcnt vmcnt(8)" ::: "memory");
  __builtin_amdgcn_sched_barrier(0);
}
DEV void barrierRaw() {
  __builtin_amdgcn_sched_barrier(0);
  __builtin_amdgcn_s_barrier();
  __builtin_amdgcn_sched_barrier(0);
}
DEV void waitLgkm0() {
  asm volatile("s_waitcnt lgkmcnt(0)" ::: "memory");
  __builtin_amdgcn_sched_barrier(0);
}

DEV float waveSum(float v) {
#pragma unroll
  for (int o = 32; o; o >>= 1) v += __shfl_xor(v, o);
  return v;
}

// ---------------- weight fp32 -> bf16 cast (batched jobs) ----------------
struct CastJob { const float* src; u16* dst; int nBlk; };
struct CastArgs { CastJob j[24]; int n; };

__global__ void cast_kernel(CastArgs a) {
  int blk = blockIdx.x;
  int i = 0;
  while (i + 1 < a.n && blk >= a.j[i].nBlk) { blk -= a.j[i].nBlk; ++i; }
  const size_t base = (size_t)blk * 2048 + threadIdx.x * 8;
  const float4* s4 = (const float4*)(a.j[i].src + base);
  const float4 v0 = s4[0], v1 = s4[1];
  short8 o;
  o[0] = (short)f2bf(v0.x); o[1] = (short)f2bf(v0.y);
  o[2] = (short)f2bf(v0.z); o[3] = (short)f2bf(v0.w);
  o[4] = (short)f2bf(v1.x); o[5] = (short)f2bf(v1.y);
  o[6] = (short)f2bf(v1.z); o[7] = (short)f2bf(v1.w);
  *(short8*)(a.j[i].dst + base) = o;
}

// ---------------- small fp32 copy (bias concat) ----------------
struct CopyJob { const float* src; float* dst; };
struct CopyArgs { CopyJob j[16]; int n; };
__global__ void bconcat_kernel(CopyArgs a) {
  const CopyJob jb = a.j[blockIdx.x];
  ((float4*)jb.dst)[threadIdx.x] = ((const float4*)jb.src)[threadIdx.x];
}

// ---------------- embedding: h = tok_W[x] + pos ----------------
__global__ void embed_kernel(const int* __restrict__ x, const float* __restrict__ tokW,
                             const float* __restrict__ pos, float* __restrict__ hF,
                             u16* __restrict__ hB) {
  const int bt = blockIdx.x;
  const int t = bt & (cfg::T - 1);
  const int tid = threadIdx.x;
  const int idx = x[bt];
  float4 v = ((const float4*)(tokW + (size_t)idx * cfg::D))[tid];
  const float4 p = ((const float4*)(pos + (size_t)t * cfg::D))[tid];
  v.x += p.x; v.y += p.y; v.z += p.z; v.w += p.w;
  ((float4*)(hF + (size_t)bt * cfg::D))[tid] = v;
  union { u16 u[4]; uint2 q; } pk;
  pk.u[0] = f2bf(v.x); pk.u[1] = f2bf(v.y); pk.u[2] = f2bf(v.z); pk.u[3] = f2bf(v.w);
  *(uint2*)(hB + (size_t)bt * cfg::D + tid * 4) = pk.q;
}

DEV void addBf4(float4& x, const u16* p, size_t off) {
  const uint2 q = *(const uint2*)(p + off);
  x.x += bf2f((u16)(q.x & 0xffffu)); x.y += bf2f((u16)(q.x >> 16));
  x.z += bf2f((u16)(q.y & 0xffffu)); x.w += bf2f((u16)(q.y >> 16));
}

// ---------------- residual + 4 bf16 split-K partials + bias + LayerNorm ----------------
__global__ void ln4_kernel(const float* __restrict__ base,
                           const u16* __restrict__ a0, const u16* __restrict__ a1,
                           const u16* __restrict__ a2, const u16* __restrict__ a3,
                           const float* __restrict__ biasv,
                           const float* __restrict__ g, const float* __restrict__ bt,
                           float* __restrict__ outF, u16* __restrict__ outB) {
  const int row = blockIdx.x, tid = threadIdx.x;
  const int lane = tid & 63, wid = tid >> 6;
  const size_t roff = (size_t)row * cfg::D;
  const size_t eoff = roff + tid * 4;
  float4 x = ((const float4*)(base + roff))[tid];
  addBf4(x, a0, eoff); addBf4(x, a1, eoff); addBf4(x, a2, eoff); addBf4(x, a3, eoff);
  {
    const float4 a = ((const float4*)biasv)[tid];
    x.x += a.x; x.y += a.y; x.z += a.z; x.w += a.w;
  }
  float s = x.x + x.y + x.z + x.w;
  float s2 = x.x * x.x + x.y * x.y + x.z * x.z + x.w * x.w;
  __shared__ float sb[8];
  s = waveSum(s); s2 = waveSum(s2);
  if (lane == 0) { sb[wid] = s; sb[4 + wid] = s2; }
  __syncthreads();
  s = sb[0] + sb[1] + sb[2] + sb[3];
  s2 = sb[4] + sb[5] + sb[6] + sb[7];
  const float mean = s * (1.f / cfg::D);
  const float rs = rsqrtf(s2 * (1.f / cfg::D) - mean * mean + 1e-5f);
  const float4 gv = ((const float4*)g)[tid];
  const float4 bv = ((const float4*)bt)[tid];
  float4 y;
  y.x = (x.x - mean) * rs * gv.x + bv.x;
  y.y = (x.y - mean) * rs * gv.y + bv.y;
  y.z = (x.z - mean) * rs * gv.z + bv.z;
  y.w = (x.w - mean) * rs * gv.w + bv.w;
  ((float4*)(outF + roff))[tid] = y;
  union { u16 u[4]; uint2 q; } pk;
  pk.u[0] = f2bf(y.x); pk.u[1] = f2bf(y.y); pk.u[2] = f2bf(y.z); pk.u[3] = f2bf(y.w);
  *(uint2*)(outB + roff + tid * 4) = pk.q;
}

// ---------------- tail: residual + partials + bias -> LN(tln) -> LN(norm) -> bf16 ----------------
__global__ void lnfin_kernel(const float* __restrict__ base,
                             const u16* __restrict__ a0, const u16* __restrict__ a1,
                             const u16* __restrict__ a2, const u16* __restrict__ a3,
                             const float* __restrict__ biasv,
                             const float* __restrict__ g1, const float* __restrict__ b1v,
                             const float* __restrict__ g2, const float* __restrict__ b2v,
                             u16* __restrict__ outB) {
  const int row = blockIdx.x, tid = threadIdx.x;
  const int lane = tid & 63, wid = tid >> 6;
  const size_t roff = (size_t)row * cfg::D;
  const size_t eoff = roff + tid * 4;
  float4 x = ((const float4*)(base + roff))[tid];
  addBf4(x, a0, eoff); addBf4(x, a1, eoff); addBf4(x, a2, eoff); addBf4(x, a3, eoff);
  {
    const float4 a = ((const float4*)biasv)[tid];
    x.x += a.x; x.y += a.y; x.z += a.z; x.w += a.w;
  }
  __shared__ float sb[8];
  // LN pass 1
  float s = x.x + x.y + x.z + x.w;
  float s2 = x.x * x.x + x.y * x.y + x.z * x.z + x.w * x.w;
  s = waveSum(s); s2 = waveSum(s2);
  if (lane == 0) { sb[wid] = s; sb[4 + wid] = s2; }
  __syncthreads();
  s = sb[0] + sb[1] + sb[2] + sb[3];
  s2 = sb[4] + sb[5] + sb[6] + sb[7];
  float mean = s * (1.f / cfg::D);
  float rs = rsqrtf(s2 * (1.f / cfg::D) - mean * mean + 1e-5f);
  const float4 g1v = ((const float4*)g1)[tid];
  const float4 b1x = ((const float4*)b1v)[tid];
  float4 y;
  y.x = (x.x - mean) * rs * g1v.x + b1x.x;
  y.y = (x.y - mean) * rs * g1v.y + b1x.y;
  y.z = (x.z - mean) * rs * g1v.z + b1x.z;
  y.w = (x.w - mean) * rs * g1v.w + b1x.w;
  // LN pass 2
  float t = y.x + y.y + y.z + y.w;
  float t2 = y.x * y.x + y.y * y.y + y.z * y.z + y.w * y.w;
  t = waveSum(t); t2 = waveSum(t2);
  __syncthreads();                 // all reads of sb done before overwrite
  if (lane == 0) { sb[wid] = t; sb[4 + wid] = t2; }
  __syncthreads();
  t = sb[0] + sb[1] + sb[2] + sb[3];
  t2 = sb[4] + sb[5] + sb[6] + sb[7];
  mean = t * (1.f / cfg::D);
  rs = rsqrtf(t2 * (1.f / cfg::D) - mean * mean + 1e-5f);
  const float4 g2v = ((const float4*)g2)[tid];
  const float4 b2x = ((const float4*)b2v)[tid];
  union { u16 u[4]; uint2 q; } pk;
  pk.u[0] = f2bf((y.x - mean) * rs * g2v.x + b2x.x);
  pk.u[1] = f2bf((y.y - mean) * rs * g2v.y + b2x.y);
  pk.u[2] = f2bf((y.z - mean) * rs * g2v.z + b2x.z);
  pk.u[3] = f2bf((y.w - mean) * rs * g2v.w + b2x.w);
  *(uint2*)(outB + roff + tid * 4) = pk.q;
}

// ---------------- V transpose: picks v-slice, [B,T,D3]->[B*H, HD, T] ----------------
__global__ void vtrans_kernel(const u16* __restrict__ v, u16* __restrict__ vtO, int vstride) {
  __shared__ u16 s[64][68];
  const int bh = blockIdx.y, b = bh >> 4, h = bh & 15;
  const int t0 = blockIdx.x * 64;
  const int tid = threadIdx.x;
  const int r2 = tid >> 3, cg = tid & 7;
#pragma unroll
  for (int p = 0; p < 2; ++p) {
    const int r = p * 32 + r2;
    const short8 val = *(const short8*)(v + (size_t)(b * cfg::T + t0 + r) * vstride + h * 64 + cg * 8);
#pragma unroll
    for (int j = 0; j < 8; ++j) s[r][cg * 8 + j] = (u16)val[j];
  }
  __syncthreads();
#pragma unroll
  for (int p = 0; p < 2; ++p) {
    const int d = p * 32 + r2;
    short8 o;
#pragma unroll
    for (int j = 0; j < 8; ++j) o[j] = (short)s[cg * 8 + j][d];
    *(short8*)(vtO + ((size_t)bh * 64 + d) * (size_t)cfg::T + t0 + cg * 8) = o;
  }
}

// ---------------- swizzled LDS staging, 128B rows ----------------
template <int NCH>
DEV void stageTile(u16* lds, const u16* src, int strideElems, int tid) {
#pragma unroll
  for (int c = 0; c < NCH / 256; ++c) {
    const int ci = c * 256 + tid;
    const int r = ci >> 3;
    const int c8 = ci & 7;
    const int sc8 = c8 ^ (r & 7);
    gload16(lds + (size_t)ci * 8, src + (size_t)r * strideElems + sc8 * 8);
  }
}
DEV short8 ldsFrag(const u16* tile, int row, int kElem) {
  const int byteoff = row * 128 + ((kElem * 2) ^ ((row & 7) << 4));
  return *(const short8*)((const char*)tile + byteoff);
}
// 64B rows (BK=32): residual 2-way bank aliasing only (free).
DEV short8 ldsFrag32(const u16* tile, int row, int kElem) {
  const int byteoff = row * 64 + ((kElem * 2) ^ (((row >> 1) & 3) << 4));
  return *(const short8*)((const char*)tile + byteoff);
}

// ---------------- flash attention: QBLK=64, grid (T/64, B*H), 256 thr ----------------
__launch_bounds__(256, 3)
__global__ void fattn_kernel(const u16* __restrict__ qkv, const u16* __restrict__ vt,
                             u16* __restrict__ o) {
  constexpr int D3 = 3 * cfg::D;
  __shared__ u16 Qs[64 * 64];
  __shared__ u16 Ks[64 * 64];
  __shared__ u16 Vs[64 * 64];
  __shared__ u16 Ps[64][72];
  const int tid = threadIdx.x, lane = tid & 63, w = tid >> 6;
  const int qt = gridDim.x - 1 - blockIdx.x;   // longest-first scheduling
  const int bh = blockIdx.y;
  const int b = bh >> 4, h = bh & 15;
  const int q0 = qt * 64;
  const int l15 = lane & 15, lq = lane >> 4;

  stageTile<512>(Qs, qkv + (size_t)(b * cfg::T + q0) * D3 + h * 64, D3, tid);
  __syncthreads();
  short8 qf[2];
#pragma unroll
  for (int kk = 0; kk < 2; ++kk)
    qf[kk] = ldsFrag(Qs, w * 16 + l15, kk * 32 + lq * 8);

  f32x4 oa[4];
  float m[4], l[4];
#pragma unroll
  for (int r = 0; r < 4; ++r) { m[r] = -1e30f; l[r] = 0.f; }
#pragma unroll
  for (int nt = 0; nt < 4; ++nt) { oa[nt][0] = 0; oa[nt][1] = 0; oa[nt][2] = 0; oa[nt][3] = 0; }

  const int nkt = qt + 1;
  const u16* kbase = qkv + (size_t)(b * cfg::T) * D3 + cfg::D + h * 64;
  const u16* vbase = vt + (size_t)bh * 64 * cfg::T;

  for (int kt = 0; kt < nkt; ++kt) {
    const int k0 = kt * 64;
    __syncthreads();
    stageTile<512>(Ks, kbase + (size_t)k0 * D3, D3, tid);
    stageTile<512>(Vs, vbase + k0, cfg::T, tid);
    __syncthreads();

    f32x4 sa[4];
#pragma unroll
    for (int nt = 0; nt < 4; ++nt) { sa[nt][0] = 0; sa[nt][1] = 0; sa[nt][2] = 0; sa[nt][3] = 0; }
#pragma unroll
    for (int kk = 0; kk < 2; ++kk) {
      short8 kf[4];
#pragma unroll
      for (int nt = 0; nt < 4; ++nt) kf[nt] = ldsFrag(Ks, nt * 16 + l15, kk * 32 + lq * 8);
#pragma unroll
      for (int nt = 0; nt < 4; ++nt)
        sa[nt] = __builtin_amdgcn_mfma_f32_16x16x32_bf16(qf[kk], kf[nt], sa[nt], 0, 0, 0);
    }

    const bool needMask = (kt >= qt);
#pragma unroll
    for (int r = 0; r < 4; ++r) {
      const int qrow = q0 + w * 16 + lq * 4 + r;
      float s[4];
#pragma unroll
      for (int nt = 0; nt < 4; ++nt) {
        s[nt] = sa[nt][r] * 0.125f;
        if (needMask && (k0 + nt * 16 + l15 > qrow)) s[nt] = -3e38f;
      }
      float rm = fmaxf(fmaxf(s[0], s[1]), fmaxf(s[2], s[3]));
#pragma unroll
      for (int off = 1; off < 16; off <<= 1) rm = fmaxf(rm, __shfl_xor(rm, off));
      const float mn = fmaxf(m[r], rm);
      const float sc = __expf(m[r] - mn);
      m[r] = mn;
      float ps = 0.f;
#pragma unroll
      for (int nt = 0; nt < 4; ++nt) {
        const float p = __expf(s[nt] - mn);
        ps += p;
        Ps[w * 16 + lq * 4 + r][nt * 16 + l15] = f2bf(p);
      }
#pragma unroll
      for (int off = 1; off < 16; off <<= 1) ps += __shfl_xor(ps, off);
      l[r] = l[r] * sc + ps;
#pragma unroll
      for (int nt = 0; nt < 4; ++nt) oa[nt][r] *= sc;
    }

#pragma unroll
    for (int kk = 0; kk < 2; ++kk) {
      short8 pa = *(const short8*)&Ps[w * 16 + l15][kk * 32 + lq * 8];
      short8 vf[4];
#pragma unroll
      for (int nt = 0; nt < 4; ++nt) vf[nt] = ldsFrag(Vs, nt * 16 + l15, kk * 32 + lq * 8);
#pragma unroll
      for (int nt = 0; nt < 4; ++nt)
        oa[nt] = __builtin_amdgcn_mfma_f32_16x16x32_bf16(pa, vf[nt], oa[nt], 0, 0, 0);
    }
  }

  u16* obase = o + (size_t)(b * cfg::T + q0 + w * 16) * cfg::D + h * 64;
#pragma unroll
  for (int r = 0; r < 4; ++r) {
    const float inv = 1.f / l[r];
    const int rl = lq * 4 + r;
#pragma unroll
    for (int nt = 0; nt < 4; ++nt)
      obase[(size_t)rl * cfg::D + nt * 16 + l15] = f2bf(oa[nt][r] * inv);
  }
}

// ---------------- bf16 MFMA GEMM: 128xBN, BK=64, single-buffer ----------------
// Split-K via blockIdx.z: K param is the per-split K; A/B column offset z*K,
// C written to Cp + z*partStride (bf16 partials; summed in ln4/lnfin).
template <int BN, int EPI, int OUTF32, int SWZ, int MMAJOR>
__launch_bounds__(256, 4)
__global__ void gemm_kernel(const u16* __restrict__ A, const u16* __restrict__ Bw,
                            const float* __restrict__ bias, void* __restrict__ Cp,
                            int lda, int ldb, int ldc, int K, long long partStride) {
  constexpr int BM = 128, BK = 64;
  constexpr int WN = BN / 2;
  constexpr int MF = 4, NF = WN / 16;
  int bx = blockIdx.x, by = blockIdx.y;
  if (SWZ) {
    const int gx = gridDim.x;
    const int nwg = gx * gridDim.y;
    const int lid = by * gx + bx;
    const int q = nwg >> 3, r = nwg & 7;
    const int xcd = lid & 7, rest = lid >> 3;
    const int nid = (xcd < r ? xcd * (q + 1) : r * (q + 1) + (xcd - r) * q) + rest;
    bx = nid % gx; by = nid / gx;
  }
  const int z = blockIdx.z;
  const u16* Ab = A + (size_t)z * K;
  const u16* Bb = Bw + (size_t)z * K;
  const int tid = threadIdx.x;
  const int lane = tid & 63;
  const int wid = tid >> 6;
  const int wr = wid >> 1, wc = wid & 1;
  const int m0 = (MMAJOR ? bx : by) * BM;
  const int n0 = (MMAJOR ? by : bx) * BN;

  __shared__ u16 As[BM][BK];
  __shared__ u16 Bs[BN][BK];

  const int nkt = K / BK;

  f32x4 acc[MF][NF];
#pragma unroll
  for (int i = 0; i < MF; ++i)
#pragma unroll
    for (int j = 0; j < NF; ++j) {
      acc[i][j][0] = 0.f; acc[i][j][1] = 0.f; acc[i][j][2] = 0.f; acc[i][j][3] = 0.f;
    }

  for (int kt = 0; kt < nkt; ++kt) {
    __syncthreads();
    const int kb = kt * BK;
    stageTile<(BM * BK) / 8>(&As[0][0], Ab + (size_t)m0 * lda + kb, lda, tid);
    stageTile<(BN * BK) / 8>(&Bs[0][0], Bb + (size_t)n0 * ldb + kb, ldb, tid);
    __syncthreads();
#pragma unroll
    for (int kk = 0; kk < BK / 32; ++kk) {
      short8 av[MF], bv[NF];
      const int kElem = kk * 32 + (lane >> 4) * 8;
#pragma unroll
      for (int mt = 0; mt < MF; ++mt)
        av[mt] = ldsFrag(&As[0][0], wr * 64 + mt * 16 + (lane & 15), kElem);
#pragma unroll
      for (int nt = 0; nt < NF; ++nt)
        bv[nt] = ldsFrag(&Bs[0][0], wc * WN + nt * 16 + (lane & 15), kElem);
#pragma unroll
      for (int mt = 0; mt < MF; ++mt)
#pragma unroll
        for (int nt = 0; nt < NF; ++nt)
          acc[mt][nt] = __builtin_amdgcn_mfma_f32_16x16x32_bf16(av[mt], bv[nt], acc[mt][nt], 0, 0, 0);
    }
  }

  const int rhi = (lane >> 4) * 4, cidx = lane & 15;
  const long long cb = (long long)z * partStride;
#pragma unroll
  for (int mt = 0; mt < MF; ++mt) {
#pragma unroll
    for (int nt = 0; nt < NF; ++nt) {
      const int col = n0 + wc * WN + nt * 16 + cidx;
      const float badd = bias ? bias[col] : 0.f;
#pragma unroll
      for (int r = 0; r < 4; ++r) {
        const int row = m0 + wr * 64 + mt * 16 + rhi + r;
        float val = acc[mt][nt][r] + badd;
        if (EPI == 1) {
          const float zz = 1.5957691216057308f * (val + 0.044715f * val * val * val);
          const float th = 1.f - 2.f / (__expf(zz) + 1.f);
          val = 0.5f * val * (1.f + th);
        }
        const size_t off = (size_t)(cb + (long long)row * ldc + col);
        if (OUTF32) ((float*)Cp)[off] = val;
        else ((u16*)Cp)[off] = f2bf(val);
      }
    }
  }
}

// ---------------- 256x256 deep-pipelined GEMM (logits): BK=32, 4 LDS buffers ----------------
__launch_bounds__(512, 1)
__global__ void gemm256c_kernel(const u16* __restrict__ A, const u16* __restrict__ Bw,
                                const float* __restrict__ bias, float* __restrict__ Cp,
                                int lda, int ldb, int ldc, int K) {
  extern __shared__ u16 lds[];   // 4 bufs x (A 8192 + B 8192) u16 = 128 KB
  int bx = blockIdx.x, by = blockIdx.y;
  {  // bijective XCD swizzle; M-major (x = M-tiles share weight tile)
    const int gx = gridDim.x;
    const int nwg = gx * gridDim.y;
    const int lid = by * gx + bx;
    const int q = nwg >> 3, r = nwg & 7;
    const int xcd = lid & 7, rest = lid >> 3;
    const int nid = (xcd < r ? xcd * (q + 1) : r * (q + 1) + (xcd - r) * q) + rest;
    bx = nid % gx; by = nid / gx;
  }
  const int tid = threadIdx.x;
  const int lane = tid & 63;
  const int wid = tid >> 6;               // 0..7
  const int wr = wid >> 2, wc = wid & 3;  // 2M x 4N; per-wave C = 128x64
  const int m0 = bx * 256;
  const int n0 = by * 256;
  const int l15 = lane & 15, lq = lane >> 4;

  const u16* Abase = A + (size_t)m0 * lda;
  const u16* Bbase = Bw + (size_t)n0 * ldb;

  auto stageHalf = [&](int ldsOff, const u16* srcBase, int ld, int kb, int h) {
    const int ci = h * 512 + tid;
    const int r = ci >> 2;
    const int sc = (ci & 3) ^ ((r >> 1) & 3);
    gload16(lds + ldsOff + (size_t)ci * 8, srcBase + (size_t)r * ld + kb + sc * 8);
  };
  auto stageA = [&](int buf, int kb) {
    stageHalf(buf * 16384, Abase, lda, kb, 0);
    stageHalf(buf * 16384, Abase, lda, kb, 1);
  };
  auto stageB = [&](int buf, int kb) {
    stageHalf(buf * 16384 + 8192, Bbase, ldb, kb, 0);
    stageHalf(buf * 16384 + 8192, Bbase, ldb, kb, 1);
  };

  f32x4 acc[8][4];
#pragma unroll
  for (int i = 0; i < 8; ++i)
#pragma unroll
    for (int j = 0; j < 4; ++j) { acc[i][j][0] = 0.f; acc[i][j][1] = 0.f; acc[i][j][2] = 0.f; acc[i][j][3] = 0.f; }

  const int nt_ = K / 32;    // 32 tiles
  for (int t = 0; t < 3; ++t) { stageA(t, t * 32); stageB(t, t * 32); }

  const int kE = lq * 8;
  for (int t = 0; t < nt_; ++t) {
    if (t <= nt_ - 3) waitVm<8>();
    else if (t == nt_ - 2) waitVm<4>();
    else waitVm<0>();
    barrierRaw();
    const int buf = t & 3;
    const u16* At = lds + buf * 16384;
    const u16* Bt = lds + buf * 16384 + 8192;
    const int nbuf = (t + 3) & 3;
    const int kb3 = (t + 3) * 32;
    const bool pf = (t + 3 < nt_);
    short8 bv[4];
#pragma unroll
    for (int nt = 0; nt < 4; ++nt)
      bv[nt] = ldsFrag32(Bt, wc * 64 + nt * 16 + l15, kE);
#pragma unroll
    for (int mh = 0; mh < 2; ++mh) {
      short8 av[4];
#pragma unroll
      for (int mt = 0; mt < 4; ++mt)
        av[mt] = ldsFrag32(At, wr * 128 + mh * 64 + mt * 16 + l15, kE);
      if (pf) {
        if (mh == 0) stageA(nbuf, kb3);
        else stageB(nbuf, kb3);
      }
      waitLgkm0();
      __builtin_amdgcn_s_setprio(1);
#pragma unroll
      for (int mt = 0; mt < 4; ++mt)
#pragma unroll
        for (int nt = 0; nt < 4; ++nt)
          acc[mh * 4 + mt][nt] = __builtin_amdgcn_mfma_f32_16x16x32_bf16(av[mt], bv[nt], acc[mh * 4 + mt][nt], 0, 0, 0);
      __builtin_amdgcn_s_setprio(0);
    }
  }

#pragma unroll
  for (int g = 0; g < 8; ++g) {
#pragma unroll
    for (int nt = 0; nt < 4; ++nt) {
      const int col = n0 + wc * 64 + nt * 16 + l15;
      const float badd = bias[col];
#pragma unroll
      for (int r = 0; r < 4; ++r) {
        const int row = m0 + wr * 128 + g * 16 + lq * 4 + r;
        Cp[(size_t)row * ldc + col] = acc[g][nt][r] + badd;
      }
    }
  }
}

// ---------------- host ----------------
extern "C" void kernel_launch(void* const* d_in, const int* in_sizes, int n_in,
                              void* d_out, int out_size, void* d_ws, size_t ws_size,
                              hipStream_t stream) {
  using namespace cfg;
  (void)in_sizes; (void)n_in; (void)out_size;
  const int* x = (const int*)d_in[0];
  const float* tokW = (const float*)d_in[2];
  const float* pos = (const float*)d_in[3];
  const float* Wq = (const float*)d_in[4];  const float* bq = (const float*)d_in[5];
  const float* Wk = (const float*)d_in[6];  const float* bk = (const float*)d_in[7];
  const float* Wv = (const float*)d_in[8];  const float* bv = (const float*)d_in[9];
  const float* Wo = (const float*)d_in[10]; const float* bo = (const float*)d_in[11];
  const float* ln1g = (const float*)d_in[12]; const float* ln1b = (const float*)d_in[13];
  const float* W1 = (const float*)d_in[14]; const float* b1 = (const float*)d_in[15];
  const float* W2 = (const float*)d_in[16]; const float* b2 = (const float*)d_in[17];
  const float* ln2g = (const float*)d_in[18]; const float* ln2b = (const float*)d_in[19];
  const float* mWq = (const float*)d_in[20]; const float* mbq = (const float*)d_in[21];
  const float* mWk = (const float*)d_in[22]; const float* mbk = (const float*)d_in[23];
  const float* mWv = (const float*)d_in[24]; const float* mbv = (const float*)d_in[25];
  const float* mWo = (const float*)d_in[26]; const float* mbo = (const float*)d_in[27];
  const float* mlng = (const float*)d_in[28]; const float* mlnb = (const float*)d_in[29];
  const float* tWq = (const float*)d_in[30]; const float* tbq = (const float*)d_in[31];
  const float* tWk = (const float*)d_in[32]; const float* tbk = (const float*)d_in[33];
  const float* tWv = (const float*)d_in[34]; const float* tbv = (const float*)d_in[35];
  const float* tWo = (const float*)d_in[36]; const float* tbo = (const float*)d_in[37];
  const float* tlng = (const float*)d_in[38]; const float* tlnb = (const float*)d_in[39];
  const float* normg = (const float*)d_in[40]; const float* normb = (const float*)d_in[41];
  const float* outW = (const float*)d_in[42]; const float* outb = (const float*)d_in[43];

  const size_t DD = (size_t)D * D;
  const long long ND = (long long)N * D;
  char* wsb = (char*)d_ws;
  size_t off = 0;
  auto alloc = [&](size_t bytes) {
    void* p = wsb + off;
    off += (bytes + 255) & ~(size_t)255;
    return p;
  };
  u16* qkvW = (u16*)alloc((size_t)L * 3 * DD * 2);   // [L][3][D][D]
  u16* mqkvW = (u16*)alloc(3 * DD * 2);
  u16* tqkvW = (u16*)alloc(3 * DD * 2);
  u16* WoB = (u16*)alloc((size_t)L * DD * 2);
  u16* W1B = (u16*)alloc((size_t)L * F * D * 2);
  u16* W2B = (u16*)alloc((size_t)L * D * F * 2);
  u16* mWoB = (u16*)alloc(DD * 2);
  u16* tWoB = (u16*)alloc(DD * 2);
  u16* outWB = (u16*)alloc((size_t)V * D * 2);
  float* biasQKV = (float*)alloc((size_t)(L + 2) * 3 * D * 4);  // per-MHA concat [bq;bk;bv]
  float* hF = (float*)alloc((size_t)N * D * 4);
  u16* hB = (u16*)alloc((size_t)N * D * 2);
  u16* pSb = (u16*)alloc((size_t)4 * N * D * 2);  // bf16 split-K partials (4 slots)
  u16* qkvB = (u16*)alloc((size_t)N * 3 * D * 2);
  u16* vtB = (u16*)alloc((size_t)N * D * 2);
  u16* oB = (u16*)alloc((size_t)N * D * 2);
  u16* f1B = (u16*)alloc((size_t)N * F * 2);
  if (off > ws_size) return;

  // ---- weight conversion fp32 -> bf16 (QKV interleaved per layer) ----
  CastArgs ca;
  int nj = 0; long total = 0;
  auto addJob = [&](const float* s, u16* dptr, size_t n) {
    ca.j[nj].src = s; ca.j[nj].dst = dptr; ca.j[nj].nBlk = (int)(n / 2048);
    total += (long)(n / 2048); ++nj;
  };
  for (int i = 0; i < L; ++i) {
    addJob(Wq + i * DD, qkvW + (size_t)i * 3 * DD, DD);
    addJob(Wk + i * DD, qkvW + (size_t)i * 3 * DD + DD, DD);
    addJob(Wv + i * DD, qkvW + (size_t)i * 3 * DD + 2 * DD, DD);
  }
  addJob(mWq, mqkvW, DD); addJob(mWk, mqkvW + DD, DD); addJob(mWv, mqkvW + 2 * DD, DD);
  addJob(tWq, tqkvW, DD); addJob(tWk, tqkvW + DD, DD); addJob(tWv, tqkvW + 2 * DD, DD);
  addJob(Wo, WoB, (size_t)L * DD);
  addJob(W1, W1B, (size_t)L * F * D);
  addJob(W2, W2B, (size_t)L * D * F);
  addJob(mWo, mWoB, DD); addJob(tWo, tWoB, DD);
  addJob(outW, outWB, (size_t)V * D);
  ca.n = nj;
  cast_kernel<<<dim3((unsigned)total), 256, 0, stream>>>(ca);

  // ---- bias concat ----
  CopyArgs cpa;
  int nc = 0;
  auto addCopy = [&](const float* s, float* dptr) { cpa.j[nc].src = s; cpa.j[nc].dst = dptr; ++nc; };
  for (int i = 0; i < L; ++i) {
    addCopy(bq + (size_t)i * D, biasQKV + (size_t)i * 3 * D);
    addCopy(bk + (size_t)i * D, biasQKV + (size_t)i * 3 * D + D);
    addCopy(bv + (size_t)i * D, biasQKV + (size_t)i * 3 * D + 2 * D);
  }
  addCopy(mbq, biasQKV + (size_t)L * 3 * D); addCopy(mbk, biasQKV + (size_t)L * 3 * D + D);
  addCopy(mbv, biasQKV + (size_t)L * 3 * D + 2 * D);
  addCopy(tbq, biasQKV + (size_t)(L + 1) * 3 * D); addCopy(tbk, biasQKV + (size_t)(L + 1) * 3 * D + D);
  addCopy(tbv, biasQKV + (size_t)(L + 1) * 3 * D + 2 * D);
  cpa.n = nc;
  bconcat_kernel<<<dim3((unsigned)nc), 256, 0, stream>>>(cpa);

  embed_kernel<<<N, 256, 0, stream>>>(x, tokW, pos, hF, hB);

  // MHA: QKV (BN=64, 768 blk), attn, o-proj split-K=4 -> bf16 partials (1024 blk).
  auto mha = [&](const u16* qkvw, const float* qkvbias, const u16* wo) {
    gemm_kernel<64, 0, 0, 0, 0><<<dim3(3 * D / 64, N / 128, 1), 256, 0, stream>>>(
        hB, qkvw, qkvbias, qkvB, D, D, 3 * D, D, 0);
    vtrans_kernel<<<dim3(T / 64, B * H), 256, 0, stream>>>(qkvB + 2 * D, vtB, 3 * D);
    fattn_kernel<<<dim3(T / 64, B * H), 256, 0, stream>>>(qkvB, vtB, oB);
    gemm_kernel<64, 0, 0, 0, 0><<<dim3(D / 64, N / 128, 4), 256, 0, stream>>>(
        oB, wo, nullptr, pSb, D, D, D, 256, ND);
  };
  auto lnMha = [&](const float* obias, const float* g, const float* b_) {
    ln4_kernel<<<N, 256, 0, stream>>>(hF, pSb, pSb + ND, pSb + 2 * ND, pSb + 3 * ND,
                                      obias, g, b_, hF, hB);
  };

  int mi = 0;
  for (int i = 0; i < L; ++i) {
    mha(qkvW + (size_t)i * 3 * DD, biasQKV + (size_t)i * 3 * D, WoB + (size_t)i * DD);
    lnMha(bo + (size_t)i * D, ln1g + (size_t)i * D, ln1b + (size_t)i * D);
    gemm_kernel<64, 1, 0, 0, 0><<<dim3(F / 64, N / 128, 1), 256, 0, stream>>>(
        hB, W1B + (size_t)i * F * D, b1 + (size_t)i * F, f1B, D, D, F, D, 0);
    // FFN2: split-K=4 (K=4096 -> 4x1024) -> bf16 partials
    gemm_kernel<64, 0, 0, 0, 0><<<dim3(D / 64, N / 128, 4), 256, 0, stream>>>(
        f1B, W2B + (size_t)i * D * F, nullptr, pSb, F, F, D, 1024, ND);
    ln4_kernel<<<N, 256, 0, stream>>>(hF, pSb, pSb + ND, pSb + 2 * ND, pSb + 3 * ND,
                                      b2 + (size_t)i * D, ln2g + (size_t)i * D,
                                      ln2b + (size_t)i * D, hF, hB);
    if (i % 3 == 2 && mi < 1) {
      mha(mqkvW, biasQKV + (size_t)L * 3 * D, mWoB);
      lnMha(mbo, mlng, mlnb);
      ++mi;
    }
  }
  // thought attention + fused tail double-LN (writes bf16 h only)
  mha(tqkvW, biasQKV + (size_t)(L + 1) * 3 * D, tWoB);
  lnfin_kernel<<<N, 256, 0, stream>>>(hF, pSb, pSb + ND, pSb + 2 * ND, pSb + 3 * ND,
                                      tbo, tlng, tlnb, normg, normb, hB);

  // logits: deep-pipelined 256x256 (128 KB dynamic LDS); fallback = measured 128x128.
  hipError_t e = hipFuncSetAttribute(
      reinterpret_cast<const void*>(gemm256c_kernel),
      hipFuncAttributeMaxDynamicSharedMemorySize, 131072);
  if (e == hipSuccess) {
    gemm256c_kernel<<<dim3(N / 256, V / 256, 1), 512, 131072, stream>>>(
        hB, outWB, outb, (float*)d_out, D, D, V, D);
  } else {
    gemm_kernel<128, 0, 1, 1, 1><<<dim3(N / 128, V / 128, 1), 256, 0, stream>>>(
        hB, outWB, outb, (float*)d_out, D, D, V, D, 0);
  }
}